// Round 1
// baseline (1069.048 us; speedup 1.0000x reference)
//
#include <hip/hip_runtime.h>
#include <hip/hip_bf16.h>
#include <math.h>

// Problem constants (fixed by the reference).
constexpr int N_I = 50000;   // interior nodes
constexpr int N_B = 2000;    // boundary nodes
constexpr int E_I = 800000;  // interior edges
constexpr int E_B = 16000;   // boundary edges
constexpr int E_T = E_I + E_B;
constexpr int SCAN_NB = (N_I + 1023) / 1024;  // 49

__device__ __forceinline__ float softplusf(float x) {
  // jax.nn.softplus = logaddexp(x, 0) = max(x,0) + log1p(exp(-|x|))
  return fmaxf(x, 0.0f) + log1pf(expf(-fabsf(x)));
}

// ---------------- CSR build (done once per call, reused by all 4 layers) ----
__global__ void k_count(const int* __restrict__ ei, const int* __restrict__ eb,
                        int* __restrict__ cnt) {
  int e = blockIdx.x * 256 + threadIdx.x;
  if (e >= E_T) return;
  int dst = (e < E_I) ? ei[E_I + e] : eb[E_B + (e - E_I)];
  atomicAdd(&cnt[dst], 1);
}

__global__ void k_scan1(const int* __restrict__ cnt, int* __restrict__ tmp,
                        int* __restrict__ bsum) {
  int t = threadIdx.x;
  int lane = t & 63, wid = t >> 6;
  int base = blockIdx.x * 1024 + t * 4;
  int c[4];
#pragma unroll
  for (int i = 0; i < 4; ++i) c[i] = (base + i < N_I) ? cnt[base + i] : 0;
  int s = c[0] + c[1] + c[2] + c[3];
  int inc = s;
#pragma unroll
  for (int d = 1; d < 64; d <<= 1) {
    int u = __shfl_up(inc, d, 64);
    if (lane >= d) inc += u;
  }
  __shared__ int wtot[4];
  if (lane == 63) wtot[wid] = inc;
  __syncthreads();
  int woff = 0;
  for (int i = 0; i < wid; ++i) woff += wtot[i];
  int excl = woff + inc - s;
  int run = excl;
#pragma unroll
  for (int i = 0; i < 4; ++i) {
    if (base + i < N_I) tmp[base + i] = run;
    run += c[i];
  }
  if (t == 255) bsum[blockIdx.x] = woff + inc;
}

__global__ void k_scan2(int* bsum) {
  int t = threadIdx.x;  // 64 threads, 1 wave
  int v = (t < SCAN_NB) ? bsum[t] : 0;
  int inc = v;
#pragma unroll
  for (int d = 1; d < 64; d <<= 1) {
    int u = __shfl_up(inc, d, 64);
    if (t >= d) inc += u;
  }
  if (t < SCAN_NB) bsum[t] = inc - v;  // exclusive
}

// NOTE: tmp and cursor may alias (same-thread read-then-write) -> no restrict.
__global__ void k_scan3(const int* tmp, const int* bsum, int* offs, int* cursor) {
  int t = threadIdx.x;
  int base = blockIdx.x * 1024 + t * 4;
  int add = bsum[blockIdx.x];
#pragma unroll
  for (int i = 0; i < 4; ++i) {
    int idx = base + i;
    if (idx < N_I) {
      int v = tmp[idx] + add;
      offs[idx] = v;
      cursor[idx] = v;
    }
  }
  if (blockIdx.x == 0 && t == 0) offs[N_I] = E_T;
}

__global__ void k_fill(const int* __restrict__ ei, const int* __restrict__ eb,
                       int* __restrict__ cursor, int* __restrict__ csr) {
  int e = blockIdx.x * 256 + threadIdx.x;
  if (e >= E_T) return;
  int src, dst;
  if (e < E_I) {
    src = ei[e];
    dst = ei[E_I + e];
  } else {
    int j = e - E_I;
    src = eb[j];        // already >= N_I (global boundary id)
    dst = eb[E_B + j];
  }
  int pos = atomicAdd(&cursor[dst], 1);
  csr[pos] = src;
}

// ---------------- boundary-value interpolation at t ------------------------
__global__ void k_bvt(const float* __restrict__ tptr, const float* __restrict__ ts,
                      const float* __restrict__ BV, float* __restrict__ out) {
  int idx = blockIdx.x * 256 + threadIdx.x;
  if (idx >= N_B * 64) return;
  float tv = tptr[0];
  int pos = 0;
#pragma unroll
  for (int i = 0; i < 8; ++i) pos += (ts[i] < tv) ? 1 : 0;  // searchsorted left
  int il = max(pos - 1, 0), ir = min(pos, 7);
  float tl = ts[il], tr = ts[ir];
  float vl = BV[il * (N_B * 64) + idx];
  float vr = BV[ir * (N_B * 64) + idx];
  bool eq = (tl == tr);
  float denom = eq ? 1.0f : (tr - tl);
  out[idx] = eq ? vl : vl + (tv - tl) * (vr - vl) / denom;
}

// ---------------- per-layer weight folding ---------------------------------
// M1 = Ws + Wu*Wm_dst, M2 = Wu*Wm_src, c1 = bs+bu+Wu*bm, c0 = bs+bu
// Stored TRANSPOSED ([k][o]) for coalesced GEMM reads.
__global__ void k_fold(const float* __restrict__ Wm, const float* __restrict__ bm,
                       const float* __restrict__ Ws, const float* __restrict__ bs,
                       const float* __restrict__ Wu, const float* __restrict__ bu,
                       int d, int so, float* __restrict__ M1T, float* __restrict__ M2T,
                       float* __restrict__ WsT, float* __restrict__ c1,
                       float* __restrict__ c0) {
  int idx = blockIdx.x * 256 + threadIdx.x;
  if (idx < d * so) {
    int o = idx % so, k = idx / so;
    const float* wu = Wu + o * 128;
    float s1 = 0.f, s2 = 0.f;
    int tw = 2 * d;
    for (int j = 0; j < 128; ++j) {
      float u = wu[j];
      s1 = fmaf(u, Wm[j * tw + d + k], s1);
      s2 = fmaf(u, Wm[j * tw + k], s2);
    }
    float wsv = Ws[o * d + k];
    M1T[k * so + o] = wsv + s1;
    M2T[k * so + o] = s2;
    WsT[k * so + o] = wsv;
  }
  if (idx < so) {
    float s = 0.f;
    for (int j = 0; j < 128; ++j) s = fmaf(Wu[idx * 128 + j], bm[j], s);
    c1[idx] = bs[idx] + bu[idx] + s;
    c0[idx] = bs[idx] + bu[idx];
  }
}

// ---------------- scatter-mean of raw features (wave per node) -------------
template <int D>
__global__ void k_agg(const float* __restrict__ X, const float* __restrict__ BVv,
                      const int* __restrict__ csr, const int* __restrict__ offs,
                      float* __restrict__ Sm) {
  int v = blockIdx.x * 4 + (threadIdx.x >> 6);
  if (v >= N_I) return;
  int lane = threadIdx.x & 63;
  int o0 = offs[v], o1 = offs[v + 1];
  float a0 = 0.f, a1 = 0.f;
  for (int p = o0; p < o1; ++p) {
    int s = csr[p];  // wave-uniform
    const float* f = (s < N_I) ? (X + (size_t)s * D) : (BVv + (size_t)(s - N_I) * D);
    a0 += f[lane];
    if (D == 128) a1 += f[lane + 64];
  }
  float inv = 1.0f / (float)max(o1 - o0, 1);
  Sm[(size_t)v * D + lane] = a0 * inv;
  if (D == 128) Sm[(size_t)v * D + 64 + lane] = a1 * inv;
}

// ---------------- node update: y = act(M1*x + M2*Sm + c1) ------------------
template <int D, int SO, bool ACT>
__global__ void k_node(const float* __restrict__ X, const float* __restrict__ Sm,
                       const float* __restrict__ M1T, const float* __restrict__ M2T,
                       const float* __restrict__ WsT, const float* __restrict__ c1,
                       const float* __restrict__ c0, const int* __restrict__ offs,
                       float* __restrict__ Y) {
  constexpr int TPN = SO / 4;   // threads per node
  constexpr int NPB = 256 / TPN;  // nodes per block
  __shared__ float lx[NPB * D];
  __shared__ float ls[NPB * D];
  int t = threadIdx.x;
  int base = blockIdx.x * NPB;
  for (int i = t; i < NPB * D; i += 256) {
    int nn = i / D, k = i % D;
    lx[i] = X[(size_t)(base + nn) * D + k];
    ls[i] = Sm[(size_t)(base + nn) * D + k];
  }
  __syncthreads();
  int g = t / TPN;
  int o = (t % TPN) * 4;
  int v = base + g;
  int deg = offs[v + 1] - offs[v];
  const float4* Wa = reinterpret_cast<const float4*>(deg > 0 ? M1T : WsT);
  const float4* Wb = reinterpret_cast<const float4*>(M2T);
  const float* cc = deg > 0 ? c1 : c0;
  float4 acc = make_float4(cc[o], cc[o + 1], cc[o + 2], cc[o + 3]);
  const float* xr = lx + g * D;
  const float* sr = ls + g * D;
#pragma unroll 8
  for (int k = 0; k < D; ++k) {
    float4 w1 = Wa[k * (SO / 4) + (o >> 2)];
    float4 w2 = Wb[k * (SO / 4) + (o >> 2)];
    float xv = xr[k], sv = sr[k];
    acc.x = fmaf(xv, w1.x, fmaf(sv, w2.x, acc.x));
    acc.y = fmaf(xv, w1.y, fmaf(sv, w2.y, acc.y));
    acc.z = fmaf(xv, w1.z, fmaf(sv, w2.z, acc.z));
    acc.w = fmaf(xv, w1.w, fmaf(sv, w2.w, acc.w));
  }
  if (ACT) {
    acc.x = softplusf(acc.x);
    acc.y = softplusf(acc.y);
    acc.z = softplusf(acc.z);
    acc.w = softplusf(acc.w);
  }
  reinterpret_cast<float4*>(Y + (size_t)v * SO)[o >> 2] = acc;
}

// ---------------- boundary update: bv' = softplus(Ws*bv + bs) --------------
template <int D, int SO>
__global__ void k_bnd(const float* __restrict__ BVin, const float* __restrict__ WsT,
                      const float* __restrict__ bs, float* __restrict__ out) {
  constexpr int TPN = SO / 4;
  constexpr int NPB = 256 / TPN;
  __shared__ float lx[NPB * D];
  int t = threadIdx.x;
  int base = blockIdx.x * NPB;
  for (int i = t; i < NPB * D; i += 256) {
    int nn = i / D, k = i % D;
    lx[i] = BVin[(size_t)(base + nn) * D + k];
  }
  __syncthreads();
  int g = t / TPN;
  int o = (t % TPN) * 4;
  int v = base + g;
  float4 acc = make_float4(bs[o], bs[o + 1], bs[o + 2], bs[o + 3]);
  const float* xr = lx + g * D;
  const float4* W4 = reinterpret_cast<const float4*>(WsT);
#pragma unroll 8
  for (int k = 0; k < D; ++k) {
    float4 w = W4[k * (SO / 4) + (o >> 2)];
    float xv = xr[k];
    acc.x = fmaf(xv, w.x, acc.x);
    acc.y = fmaf(xv, w.y, acc.y);
    acc.z = fmaf(xv, w.z, acc.z);
    acc.w = fmaf(xv, w.w, acc.w);
  }
  acc.x = softplusf(acc.x);
  acc.y = softplusf(acc.y);
  acc.z = softplusf(acc.z);
  acc.w = softplusf(acc.w);
  reinterpret_cast<float4*>(out + (size_t)v * SO)[o >> 2] = acc;
}

extern "C" void kernel_launch(void* const* d_in, const int* in_sizes, int n_in,
                              void* d_out, int out_size, void* d_ws, size_t ws_size,
                              hipStream_t stream) {
  const float* t_in = (const float*)d_in[0];
  const float* x_int = (const float*)d_in[1];
  const float* bvals = (const float*)d_in[2];
  const int* ei = (const int*)d_in[3];
  const int* eb = (const int*)d_in[4];
  const float* ts = (const float*)d_in[5];
  const float* W[4][6];
  for (int l = 0; l < 4; ++l)
    for (int j = 0; j < 6; ++j) W[l][j] = (const float*)d_in[6 + l * 6 + j];
  // j: 0=Wm 1=bm 2=Ws 3=bs 4=Wu 5=bu

  char* ws = (char*)d_ws;
  size_t off = 0;
  auto alloc = [&](size_t bytes) {
    void* p = ws + off;
    off = (off + bytes + 255) & ~(size_t)255;
    return p;
  };
  int* cnt = (int*)alloc(N_I * 4);
  int* offs = (int*)alloc((N_I + 1) * 4);
  int* cursor = (int*)alloc(N_I * 4);
  int* csr = (int*)alloc((size_t)E_T * 4);
  int* bsum = (int*)alloc(64 * 4);
  float* bv1 = (float*)alloc((size_t)N_B * 64 * 4);
  float* bv2 = (float*)alloc((size_t)N_B * 128 * 4);
  float* bv3 = (float*)alloc((size_t)N_B * 128 * 4);
  float* bv4 = (float*)alloc((size_t)N_B * 128 * 4);
  float* Sm = (float*)alloc((size_t)N_I * 128 * 4);
  float* xA = (float*)alloc((size_t)N_I * 128 * 4);
  float* xB = (float*)alloc((size_t)N_I * 128 * 4);
  float* fold[4];
  for (int l = 0; l < 4; ++l) fold[l] = (float*)alloc((size_t)(3 * 16384 + 256) * 4);
  (void)ws_size;
  (void)in_sizes;
  (void)n_in;
  (void)out_size;

  hipMemsetAsync(cnt, 0, N_I * 4, stream);
  int egrid = (E_T + 255) / 256;
  k_count<<<egrid, 256, 0, stream>>>(ei, eb, cnt);
  k_scan1<<<SCAN_NB, 256, 0, stream>>>(cnt, cursor /*tmp*/, bsum);
  k_scan2<<<1, 64, 0, stream>>>(bsum);
  k_scan3<<<SCAN_NB, 256, 0, stream>>>(cursor, bsum, offs, cursor);
  k_fill<<<egrid, 256, 0, stream>>>(ei, eb, cursor, csr);
  k_bvt<<<(N_B * 64 + 255) / 256, 256, 0, stream>>>(t_in, ts, bvals, bv1);

  int ds[4] = {64, 128, 128, 128};
  int sos[4] = {128, 128, 128, 64};
  for (int l = 0; l < 4; ++l) {
    float* M1T = fold[l];
    float* M2T = fold[l] + 16384;
    float* WsT = fold[l] + 32768;
    float* c1 = fold[l] + 49152;
    float* c0 = fold[l] + 49152 + 128;
    int tot = ds[l] * sos[l];
    k_fold<<<(tot + 255) / 256, 256, 0, stream>>>(W[l][0], W[l][1], W[l][2], W[l][3],
                                                  W[l][4], W[l][5], ds[l], sos[l], M1T,
                                                  M2T, WsT, c1, c0);
  }

  // Layer 1: D=64 -> 128
  k_agg<64><<<N_I / 4, 256, 0, stream>>>(x_int, bv1, csr, offs, Sm);
  k_node<64, 128, true><<<N_I / 8, 256, 0, stream>>>(
      x_int, Sm, fold[0], fold[0] + 16384, fold[0] + 32768, fold[0] + 49152,
      fold[0] + 49152 + 128, offs, xA);
  k_bnd<64, 128><<<N_B / 8, 256, 0, stream>>>(bv1, fold[0] + 32768, W[0][3], bv2);

  // Layer 2: 128 -> 128
  k_agg<128><<<N_I / 4, 256, 0, stream>>>(xA, bv2, csr, offs, Sm);
  k_node<128, 128, true><<<N_I / 8, 256, 0, stream>>>(
      xA, Sm, fold[1], fold[1] + 16384, fold[1] + 32768, fold[1] + 49152,
      fold[1] + 49152 + 128, offs, xB);
  k_bnd<128, 128><<<N_B / 8, 256, 0, stream>>>(bv2, fold[1] + 32768, W[1][3], bv3);

  // Layer 3: 128 -> 128
  k_agg<128><<<N_I / 4, 256, 0, stream>>>(xB, bv3, csr, offs, Sm);
  k_node<128, 128, true><<<N_I / 8, 256, 0, stream>>>(
      xB, Sm, fold[2], fold[2] + 16384, fold[2] + 32768, fold[2] + 49152,
      fold[2] + 49152 + 128, offs, xA);
  k_bnd<128, 128><<<N_B / 8, 256, 0, stream>>>(bv3, fold[2] + 32768, W[2][3], bv4);

  // Layer 4: 128 -> 64, no activation, straight to d_out
  k_agg<128><<<N_I / 4, 256, 0, stream>>>(xA, bv4, csr, offs, Sm);
  k_node<128, 64, false><<<N_I / 16, 256, 0, stream>>>(
      xA, Sm, fold[3], fold[3] + 16384, fold[3] + 32768, fold[3] + 49152,
      fold[3] + 49152 + 128, offs, (float*)d_out);
}

// Round 3
// 754.635 us; speedup vs baseline: 1.4166x; 1.4166x over previous
//
#include <hip/hip_runtime.h>
#include <hip/hip_bf16.h>
#include <math.h>

// Problem constants (fixed by the reference).
constexpr int N_I = 50000;   // interior nodes
constexpr int N_B = 2000;    // boundary nodes
constexpr int E_I = 800000;  // interior edges
constexpr int E_B = 16000;   // boundary edges
constexpr int E_T = E_I + E_B;
constexpr int SCAN_NB = (N_I + 1023) / 1024;  // 49

using short8 = __attribute__((ext_vector_type(8))) short;
using f32x16 = __attribute__((ext_vector_type(16))) float;

__device__ __forceinline__ float softplusf(float x) {
  return fmaxf(x, 0.0f) + log1pf(expf(-fabsf(x)));
}
__device__ __forceinline__ float b2f(ushort u) {
  return __uint_as_float((uint)u << 16);
}
__device__ __forceinline__ ushort f2b(float f) {
  __hip_bfloat16 h = __float2bfloat16(f);  // RNE
  return *reinterpret_cast<ushort*>(&h);
}

// ---------------- CSR build (once per call, reused by all 4 layers) --------
__global__ void k_count(const int* __restrict__ ei, const int* __restrict__ eb,
                        int* __restrict__ cnt) {
  int e = blockIdx.x * 256 + threadIdx.x;
  if (e >= E_T) return;
  int dst = (e < E_I) ? ei[E_I + e] : eb[E_B + (e - E_I)];
  atomicAdd(&cnt[dst], 1);
}

__global__ void k_scan1(const int* __restrict__ cnt, int* __restrict__ tmp,
                        int* __restrict__ bsum) {
  int t = threadIdx.x;
  int lane = t & 63, wid = t >> 6;
  int base = blockIdx.x * 1024 + t * 4;
  int c[4];
#pragma unroll
  for (int i = 0; i < 4; ++i) c[i] = (base + i < N_I) ? cnt[base + i] : 0;
  int s = c[0] + c[1] + c[2] + c[3];
  int inc = s;
#pragma unroll
  for (int d = 1; d < 64; d <<= 1) {
    int u = __shfl_up(inc, d, 64);
    if (lane >= d) inc += u;
  }
  __shared__ int wtot[4];
  if (lane == 63) wtot[wid] = inc;
  __syncthreads();
  int woff = 0;
  for (int i = 0; i < wid; ++i) woff += wtot[i];
  int excl = woff + inc - s;
  int run = excl;
#pragma unroll
  for (int i = 0; i < 4; ++i) {
    if (base + i < N_I) tmp[base + i] = run;
    run += c[i];
  }
  if (t == 255) bsum[blockIdx.x] = woff + inc;
}

__global__ void k_scan2(int* bsum) {
  int t = threadIdx.x;  // 64 threads, 1 wave
  int v = (t < SCAN_NB) ? bsum[t] : 0;
  int inc = v;
#pragma unroll
  for (int d = 1; d < 64; d <<= 1) {
    int u = __shfl_up(inc, d, 64);
    if (t >= d) inc += u;
  }
  if (t < SCAN_NB) bsum[t] = inc - v;  // exclusive
}

// NOTE: tmp and cursor may alias (same-thread read-then-write) -> no restrict.
__global__ void k_scan3(const int* tmp, const int* bsum, int* offs, int* cursor) {
  int t = threadIdx.x;
  int base = blockIdx.x * 1024 + t * 4;
  int add = bsum[blockIdx.x];
#pragma unroll
  for (int i = 0; i < 4; ++i) {
    int idx = base + i;
    if (idx < N_I) {
      int v = tmp[idx] + add;
      offs[idx] = v;
      cursor[idx] = v;
    }
  }
  if (blockIdx.x == 0 && t == 0) offs[N_I] = E_T;
}

__global__ void k_fill(const int* __restrict__ ei, const int* __restrict__ eb,
                       int* __restrict__ cursor, int* __restrict__ csr) {
  int e = blockIdx.x * 256 + threadIdx.x;
  if (e >= E_T) return;
  int src, dst;
  if (e < E_I) {
    src = ei[e];
    dst = ei[E_I + e];
  } else {
    int j = e - E_I;
    src = eb[j];        // already >= N_I (global boundary id)
    dst = eb[E_B + j];
  }
  int pos = atomicAdd(&cursor[dst], 1);
  csr[pos] = src;
}

__global__ void k_zlist(const int* __restrict__ offs, int* __restrict__ zcnt,
                        int* __restrict__ zlist) {
  int v = blockIdx.x * 256 + threadIdx.x;
  if (v >= N_I) return;
  if (offs[v + 1] == offs[v]) {
    int p = atomicAdd(zcnt, 1);
    zlist[p] = v;
  }
}

// ---------------- boundary-value interpolation at t (fp32) -----------------
__global__ void k_bvt(const float* __restrict__ tptr, const float* __restrict__ ts,
                      const float* __restrict__ BV, float* __restrict__ out) {
  int idx = blockIdx.x * 256 + threadIdx.x;
  if (idx >= N_B * 64) return;
  float tv = tptr[0];
  int pos = 0;
#pragma unroll
  for (int i = 0; i < 8; ++i) pos += (ts[i] < tv) ? 1 : 0;  // searchsorted left
  int il = max(pos - 1, 0), ir = min(pos, 7);
  float tl = ts[il], tr = ts[ir];
  float vl = BV[il * (N_B * 64) + idx];
  float vr = BV[ir * (N_B * 64) + idx];
  bool eq = (tl == tr);
  float denom = eq ? 1.0f : (tr - tl);
  out[idx] = eq ? vl : vl + (tv - tl) * (vr - vl) / denom;
}

// ---------------- per-layer weight folding ---------------------------------
// M1 = Ws + Wu*Wm_dst, M2 = Wu*Wm_src, c1 = bs+bu+Wu*bm, c0 = bs+bu
// M1/M2 pre-split into bf16 hi/lo pairs, stored [o][k] row-major
// (MFMA B-frag = one contiguous 16B read). WsT fp32 [k][o] for bnd/fixup.
__global__ void k_fold(const float* __restrict__ Wm, const float* __restrict__ bm,
                       const float* __restrict__ Ws, const float* __restrict__ bs,
                       const float* __restrict__ Wu, const float* __restrict__ bu,
                       int d, int so,
                       ushort* __restrict__ M1h, ushort* __restrict__ M1l,
                       ushort* __restrict__ M2h, ushort* __restrict__ M2l,
                       float* __restrict__ WsT, float* __restrict__ c1,
                       float* __restrict__ c0) {
  int idx = blockIdx.x * 256 + threadIdx.x;
  if (idx < d * so) {
    int o = idx % so, k = idx / so;
    const float* wu = Wu + o * 128;
    float s1 = 0.f, s2 = 0.f;
    int tw = 2 * d;
    for (int j = 0; j < 128; ++j) {
      float u = wu[j];
      s1 = fmaf(u, Wm[j * tw + d + k], s1);
      s2 = fmaf(u, Wm[j * tw + k], s2);
    }
    float wsv = Ws[o * d + k];
    float m1 = wsv + s1;
    ushort h1 = f2b(m1);
    M1h[o * d + k] = h1;
    M1l[o * d + k] = f2b(m1 - b2f(h1));
    ushort h2 = f2b(s2);
    M2h[o * d + k] = h2;
    M2l[o * d + k] = f2b(s2 - b2f(h2));
    WsT[k * so + o] = wsv;
  }
  if (idx < so) {
    float s = 0.f;
    for (int j = 0; j < 128; ++j) s = fmaf(Wu[idx * 128 + j], bm[j], s);
    c1[idx] = bs[idx] + bu[idx] + s;
    c0[idx] = bs[idx] + bu[idx];
  }
}

// ---------------- scatter-mean of raw features (wave per node, fp32) -------
template <int D>
__global__ void k_agg(const float* __restrict__ X, const float* __restrict__ BVv,
                      const int* __restrict__ csr, const int* __restrict__ offs,
                      float* __restrict__ Sm) {
  int v = blockIdx.x * 4 + (threadIdx.x >> 6);
  if (v >= N_I) return;
  int lane = threadIdx.x & 63;
  int o0 = offs[v], o1 = offs[v + 1];
  float a0 = 0.f, a1 = 0.f;
  for (int p = o0; p < o1; ++p) {
    int s = csr[p];  // wave-uniform
    const float* f = (s < N_I) ? (X + (size_t)s * D) : (BVv + (size_t)(s - N_I) * D);
    a0 += f[lane];
    if (D == 128) a1 += f[lane + 64];
  }
  float inv = 1.0f / (float)max(o1 - o0, 1);
  Sm[(size_t)v * D + lane] = a0 * inv;
  if (D == 128) Sm[(size_t)v * D + 64 + lane] = a1 * inv;
}

// ---------------- node update GEMM: Y = act(X*M1^T + Sm*M2^T + c1) ---------
// One wave per 32-row tile, split-bf16 (hi+lo) MFMA for ~fp32 accuracy:
//   A = Ah + Al (on-the-fly split of fp32 X), W = Wh + Wl (pre-split).
//   acc += Ah*Wh + Al*Wh + Ah*Wl   (Al*Wl term ~2^-18, dropped)
// mfma_f32_32x32x16_bf16 layout:
//   A: row = lane&31, k = (lane>>5)*8 + e ;  B: col = lane&31, same k
//   C/D: col = lane&31, row = (r&3) + 8*(r>>2) + 4*(lane>>5)   [m74/m101]
template <int D, int SO, bool ACT>
__global__ __launch_bounds__(64) void k_mm(
    const float* __restrict__ X, const float* __restrict__ Sm,
    const ushort* __restrict__ M1h, const ushort* __restrict__ M1l,
    const ushort* __restrict__ M2h, const ushort* __restrict__ M2l,
    const float* __restrict__ c1, float* __restrict__ Y) {
  constexpr int NT = SO / 32;
  int tile = blockIdx.x;
  int lane = threadIdx.x;
  int l31 = lane & 31, hi5 = lane >> 5;
  int row = tile * 32 + l31;
  int rrow = min(row, N_I - 1);  // clamp loads; stores are bounds-checked
  f32x16 acc[NT];
#pragma unroll
  for (int ct = 0; ct < NT; ++ct) {
    float b = c1[ct * 32 + l31];
#pragma unroll
    for (int r = 0; r < 16; ++r) acc[ct][r] = b;
  }
#pragma unroll
  for (int src = 0; src < 2; ++src) {
    const float* Ap = src == 0 ? X : Sm;
    const ushort* Wh = src == 0 ? M1h : M2h;
    const ushort* Wl = src == 0 ? M1l : M2l;
#pragma unroll
    for (int ks = 0; ks < D / 16; ++ks) {
      const float* ab = Ap + (size_t)rrow * D + ks * 16 + hi5 * 8;
      float4 f0 = reinterpret_cast<const float4*>(ab)[0];
      float4 f1 = reinterpret_cast<const float4*>(ab)[1];
      float av[8] = {f0.x, f0.y, f0.z, f0.w, f1.x, f1.y, f1.z, f1.w};
      short8 ah, al;
#pragma unroll
      for (int j = 0; j < 8; ++j) {
        ushort hb = f2b(av[j]);
        ah[j] = (short)hb;
        al[j] = (short)f2b(av[j] - b2f(hb));
      }
#pragma unroll
      for (int ct = 0; ct < NT; ++ct) {
        size_t wo = (size_t)(ct * 32 + l31) * D + ks * 16 + hi5 * 8;
        short8 wh = *reinterpret_cast<const short8*>(Wh + wo);
        short8 wl = *reinterpret_cast<const short8*>(Wl + wo);
        acc[ct] = __builtin_amdgcn_mfma_f32_32x32x16_bf16(ah, wh, acc[ct], 0, 0, 0);
        acc[ct] = __builtin_amdgcn_mfma_f32_32x32x16_bf16(al, wh, acc[ct], 0, 0, 0);
        acc[ct] = __builtin_amdgcn_mfma_f32_32x32x16_bf16(ah, wl, acc[ct], 0, 0, 0);
      }
    }
  }
#pragma unroll
  for (int ct = 0; ct < NT; ++ct) {
    int col = ct * 32 + l31;
#pragma unroll
    for (int r = 0; r < 16; ++r) {
      int rit = (r & 3) + 8 * (r >> 2) + 4 * hi5;
      int grow = tile * 32 + rit;
      if (grow < N_I) {
        float v = acc[ct][r];
        if (ACT) v = softplusf(v);
        Y[(size_t)grow * SO + col] = v;
      }
    }
  }
}

// ---------------- deg==0 fixup: y = act(Ws*x + c0) -------------------------
template <int D, int SO, bool ACT>
__global__ void k_fix(const int* __restrict__ zcnt, const int* __restrict__ zlist,
                      const float* __restrict__ X, const float* __restrict__ WsT,
                      const float* __restrict__ c0, float* __restrict__ Y) {
  int nz = zcnt[0];
  int o = threadIdx.x;
  if (o >= SO) return;
  for (int i = 0; i < nz; ++i) {
    int v = zlist[i];
    float s = c0[o];
    for (int k = 0; k < D; ++k) s = fmaf(WsT[k * SO + o], X[(size_t)v * D + k], s);
    if (ACT) s = softplusf(s);
    Y[(size_t)v * SO + o] = s;
  }
}

// ---------------- boundary update: bv' = softplus(Ws*bv + bs) --------------
template <int D, int SO>
__global__ void k_bnd(const float* __restrict__ BVin, const float* __restrict__ WsT,
                      const float* __restrict__ bs, float* __restrict__ out) {
  constexpr int TPN = SO / 4;
  constexpr int NPB = 256 / TPN;
  __shared__ float lx[NPB * D];
  int t = threadIdx.x;
  int base = blockIdx.x * NPB;
  for (int i = t; i < NPB * D; i += 256) lx[i] = BVin[(size_t)base * D + i];
  __syncthreads();
  int g = t / TPN;
  int o = (t % TPN) * 4;
  int v = base + g;
  float4 acc = make_float4(bs[o], bs[o + 1], bs[o + 2], bs[o + 3]);
  const float* xr = lx + g * D;
  const float4* W4 = reinterpret_cast<const float4*>(WsT);
#pragma unroll 8
  for (int k = 0; k < D; ++k) {
    float4 w = W4[k * (SO / 4) + (o >> 2)];
    float xv = xr[k];
    acc.x = fmaf(xv, w.x, acc.x);
    acc.y = fmaf(xv, w.y, acc.y);
    acc.z = fmaf(xv, w.z, acc.z);
    acc.w = fmaf(xv, w.w, acc.w);
  }
  float4 ov;
  ov.x = softplusf(acc.x);
  ov.y = softplusf(acc.y);
  ov.z = softplusf(acc.z);
  ov.w = softplusf(acc.w);
  reinterpret_cast<float4*>(out + (size_t)v * SO)[o >> 2] = ov;
}

extern "C" void kernel_launch(void* const* d_in, const int* in_sizes, int n_in,
                              void* d_out, int out_size, void* d_ws, size_t ws_size,
                              hipStream_t stream) {
  const float* t_in = (const float*)d_in[0];
  const float* x_int = (const float*)d_in[1];
  const float* bvals = (const float*)d_in[2];
  const int* ei = (const int*)d_in[3];
  const int* eb = (const int*)d_in[4];
  const float* ts = (const float*)d_in[5];
  const float* W[4][6];
  for (int l = 0; l < 4; ++l)
    for (int j = 0; j < 6; ++j) W[l][j] = (const float*)d_in[6 + l * 6 + j];
  // j: 0=Wm 1=bm 2=Ws 3=bs 4=Wu 5=bu

  char* ws = (char*)d_ws;
  size_t off = 0;
  auto alloc = [&](size_t bytes) {
    void* p = ws + off;
    off = (off + bytes + 255) & ~(size_t)255;
    return p;
  };
  int* cnt = (int*)alloc(N_I * 4);
  int* offs = (int*)alloc((N_I + 1) * 4);
  int* cursor = (int*)alloc(N_I * 4);
  int* csr = (int*)alloc((size_t)E_T * 4);
  int* bsum = (int*)alloc(64 * 4);
  int* zcnt = (int*)alloc(4);
  int* zlist = (int*)alloc(N_I * 4);
  float* bv1 = (float*)alloc((size_t)N_B * 64 * 4);
  float* bv2 = (float*)alloc((size_t)N_B * 128 * 4);
  float* bv3 = (float*)alloc((size_t)N_B * 128 * 4);
  float* bv4 = (float*)alloc((size_t)N_B * 128 * 4);
  float* Sm = (float*)alloc((size_t)N_I * 128 * 4);
  float* xA = (float*)alloc((size_t)N_I * 128 * 4);
  float* xB = (float*)alloc((size_t)N_I * 128 * 4);
  ushort *M1h[4], *M1l[4], *M2h[4], *M2l[4];
  float *WsT[4], *c1[4], *c0[4];
  for (int l = 0; l < 4; ++l) {
    M1h[l] = (ushort*)alloc(16384 * 2);
    M1l[l] = (ushort*)alloc(16384 * 2);
    M2h[l] = (ushort*)alloc(16384 * 2);
    M2l[l] = (ushort*)alloc(16384 * 2);
    WsT[l] = (float*)alloc(16384 * 4);
    c1[l] = (float*)alloc(128 * 4);
    c0[l] = (float*)alloc(128 * 4);
  }
  (void)ws_size; (void)in_sizes; (void)n_in; (void)out_size;

  hipMemsetAsync(cnt, 0, N_I * 4, stream);
  hipMemsetAsync(zcnt, 0, 4, stream);
  int egrid = (E_T + 255) / 256;
  k_count<<<egrid, 256, 0, stream>>>(ei, eb, cnt);
  k_scan1<<<SCAN_NB, 256, 0, stream>>>(cnt, cursor /*tmp*/, bsum);
  k_scan2<<<1, 64, 0, stream>>>(bsum);
  k_scan3<<<SCAN_NB, 256, 0, stream>>>(cursor, bsum, offs, cursor);
  k_fill<<<egrid, 256, 0, stream>>>(ei, eb, cursor, csr);
  k_zlist<<<(N_I + 255) / 256, 256, 0, stream>>>(offs, zcnt, zlist);
  k_bvt<<<(N_B * 64 + 255) / 256, 256, 0, stream>>>(t_in, ts, bvals, bv1);

  int ds[4] = {64, 128, 128, 128};
  int sos[4] = {128, 128, 128, 64};
  for (int l = 0; l < 4; ++l) {
    int tot = ds[l] * sos[l];
    k_fold<<<(tot + 255) / 256, 256, 0, stream>>>(
        W[l][0], W[l][1], W[l][2], W[l][3], W[l][4], W[l][5], ds[l], sos[l],
        M1h[l], M1l[l], M2h[l], M2l[l], WsT[l], c1[l], c0[l]);
  }

  constexpr int MM_GRID = (N_I + 31) / 32;  // 1563 single-wave blocks
  constexpr int BND_GRID = N_B / 8;         // NPB==8 for all layers -> 250

  // Layer 1: D=64 -> 128
  k_agg<64><<<N_I / 4, 256, 0, stream>>>(x_int, bv1, csr, offs, Sm);
  k_mm<64, 128, true><<<MM_GRID, 64, 0, stream>>>(x_int, Sm, M1h[0], M1l[0], M2h[0],
                                                  M2l[0], c1[0], xA);
  k_fix<64, 128, true><<<1, 128, 0, stream>>>(zcnt, zlist, x_int, WsT[0], c0[0], xA);
  k_bnd<64, 128><<<BND_GRID, 256, 0, stream>>>(bv1, WsT[0], W[0][3], bv2);

  // Layer 2: 128 -> 128
  k_agg<128><<<N_I / 4, 256, 0, stream>>>(xA, bv2, csr, offs, Sm);
  k_mm<128, 128, true><<<MM_GRID, 64, 0, stream>>>(xA, Sm, M1h[1], M1l[1], M2h[1],
                                                   M2l[1], c1[1], xB);
  k_fix<128, 128, true><<<1, 128, 0, stream>>>(zcnt, zlist, xA, WsT[1], c0[1], xB);
  k_bnd<128, 128><<<BND_GRID, 256, 0, stream>>>(bv2, WsT[1], W[1][3], bv3);

  // Layer 3: 128 -> 128
  k_agg<128><<<N_I / 4, 256, 0, stream>>>(xB, bv3, csr, offs, Sm);
  k_mm<128, 128, true><<<MM_GRID, 64, 0, stream>>>(xB, Sm, M1h[2], M1l[2], M2h[2],
                                                   M2l[2], c1[2], xA);
  k_fix<128, 128, true><<<1, 128, 0, stream>>>(zcnt, zlist, xB, WsT[2], c0[2], xA);
  k_bnd<128, 128><<<BND_GRID, 256, 0, stream>>>(bv3, WsT[2], W[2][3], bv4);

  // Layer 4: 128 -> 64, no activation, fp32 straight to d_out
  k_agg<128><<<N_I / 4, 256, 0, stream>>>(xA, bv4, csr, offs, Sm);
  k_mm<128, 64, false><<<MM_GRID, 64, 0, stream>>>(xA, Sm, M1h[3], M1l[3], M2h[3],
                                                   M2l[3], c1[3], (float*)d_out);
  k_fix<128, 64, false><<<1, 128, 0, stream>>>(zcnt, zlist, xA, WsT[3], c0[3],
                                               (float*)d_out);
}

// Round 4
// 636.533 us; speedup vs baseline: 1.6795x; 1.1855x over previous
//
#include <hip/hip_runtime.h>
#include <hip/hip_bf16.h>
#include <math.h>

// Problem constants (fixed by the reference).
constexpr int N_I = 50000;   // interior nodes
constexpr int N_B = 2000;    // boundary nodes
constexpr int E_I = 800000;  // interior edges
constexpr int E_B = 16000;   // boundary edges
constexpr int E_T = E_I + E_B;
constexpr int SCAN_NB = (N_I + 1023) / 1024;  // 49

using short8 = __attribute__((ext_vector_type(8))) short;
using f32x16 = __attribute__((ext_vector_type(16))) float;

__device__ __forceinline__ float softplusf(float x) {
  return fmaxf(x, 0.0f) + log1pf(expf(-fabsf(x)));
}
__device__ __forceinline__ float b2f(ushort u) {
  return __uint_as_float((uint)u << 16);
}
__device__ __forceinline__ ushort f2b(float f) {
  __hip_bfloat16 h = __float2bfloat16(f);  // RNE
  return *reinterpret_cast<ushort*>(&h);
}

// ---------------- CSR build (once per call, reused by all 4 layers) --------
__global__ void k_count(const int* __restrict__ ei, const int* __restrict__ eb,
                        int* __restrict__ cnt) {
  int e = blockIdx.x * 256 + threadIdx.x;
  if (e >= E_T) return;
  int dst = (e < E_I) ? ei[E_I + e] : eb[E_B + (e - E_I)];
  atomicAdd(&cnt[dst], 1);
}

__global__ void k_scan1(const int* __restrict__ cnt, int* __restrict__ tmp,
                        int* __restrict__ bsum) {
  int t = threadIdx.x;
  int lane = t & 63, wid = t >> 6;
  int base = blockIdx.x * 1024 + t * 4;
  int c[4];
#pragma unroll
  for (int i = 0; i < 4; ++i) c[i] = (base + i < N_I) ? cnt[base + i] : 0;
  int s = c[0] + c[1] + c[2] + c[3];
  int inc = s;
#pragma unroll
  for (int d = 1; d < 64; d <<= 1) {
    int u = __shfl_up(inc, d, 64);
    if (lane >= d) inc += u;
  }
  __shared__ int wtot[4];
  if (lane == 63) wtot[wid] = inc;
  __syncthreads();
  int woff = 0;
  for (int i = 0; i < wid; ++i) woff += wtot[i];
  int excl = woff + inc - s;
  int run = excl;
#pragma unroll
  for (int i = 0; i < 4; ++i) {
    if (base + i < N_I) tmp[base + i] = run;
    run += c[i];
  }
  if (t == 255) bsum[blockIdx.x] = woff + inc;
}

__global__ void k_scan2(int* bsum) {
  int t = threadIdx.x;  // 64 threads, 1 wave
  int v = (t < SCAN_NB) ? bsum[t] : 0;
  int inc = v;
#pragma unroll
  for (int d = 1; d < 64; d <<= 1) {
    int u = __shfl_up(inc, d, 64);
    if (t >= d) inc += u;
  }
  if (t < SCAN_NB) bsum[t] = inc - v;  // exclusive
}

// NOTE: tmp and cursor may alias (same-thread read-then-write) -> no restrict.
__global__ void k_scan3(const int* tmp, const int* bsum, int* offs, int* cursor) {
  int t = threadIdx.x;
  int base = blockIdx.x * 1024 + t * 4;
  int add = bsum[blockIdx.x];
#pragma unroll
  for (int i = 0; i < 4; ++i) {
    int idx = base + i;
    if (idx < N_I) {
      int v = tmp[idx] + add;
      offs[idx] = v;
      cursor[idx] = v;
    }
  }
  if (blockIdx.x == 0 && t == 0) offs[N_I] = E_T;
}

__global__ void k_fill(const int* __restrict__ ei, const int* __restrict__ eb,
                       int* __restrict__ cursor, int* __restrict__ csr) {
  int e = blockIdx.x * 256 + threadIdx.x;
  if (e >= E_T) return;
  int src, dst;
  if (e < E_I) {
    src = ei[e];
    dst = ei[E_I + e];
  } else {
    int j = e - E_I;
    src = eb[j];        // already >= N_I (global boundary id)
    dst = eb[E_B + j];
  }
  int pos = atomicAdd(&cursor[dst], 1);
  csr[pos] = src;
}

__global__ void k_zlist(const int* __restrict__ offs, int* __restrict__ zcnt,
                        int* __restrict__ zlist) {
  int v = blockIdx.x * 256 + threadIdx.x;
  if (v >= N_I) return;
  if (offs[v + 1] == offs[v]) {
    int p = atomicAdd(zcnt, 1);
    zlist[p] = v;
  }
}

// ---------------- boundary-value interpolation at t ------------------------
__global__ void k_bvt(const float* __restrict__ tptr, const float* __restrict__ ts,
                      const float* __restrict__ BV, float* __restrict__ out,
                      ushort* __restrict__ outh) {
  int idx = blockIdx.x * 256 + threadIdx.x;
  if (idx >= N_B * 64) return;
  float tv = tptr[0];
  int pos = 0;
#pragma unroll
  for (int i = 0; i < 8; ++i) pos += (ts[i] < tv) ? 1 : 0;  // searchsorted left
  int il = max(pos - 1, 0), ir = min(pos, 7);
  float tl = ts[il], tr = ts[ir];
  float vl = BV[il * (N_B * 64) + idx];
  float vr = BV[ir * (N_B * 64) + idx];
  bool eq = (tl == tr);
  float denom = eq ? 1.0f : (tr - tl);
  float v = eq ? vl : vl + (tv - tl) * (vr - vl) / denom;
  out[idx] = v;
  outh[idx] = f2b(v);
}

// ---------------- x_int fp32 -> split bf16 hi/lo ---------------------------
__global__ void k_cvt(const float* __restrict__ in, ushort* __restrict__ oh,
                      ushort* __restrict__ ol, int n4) {
  int i = blockIdx.x * 256 + threadIdx.x;
  if (i >= n4) return;
  float4 v = reinterpret_cast<const float4*>(in)[i];
  ushort4 h, l;
  h.x = f2b(v.x); l.x = f2b(v.x - b2f(h.x));
  h.y = f2b(v.y); l.y = f2b(v.y - b2f(h.y));
  h.z = f2b(v.z); l.z = f2b(v.z - b2f(h.z));
  h.w = f2b(v.w); l.w = f2b(v.w - b2f(h.w));
  reinterpret_cast<ushort4*>(oh)[i] = h;
  reinterpret_cast<ushort4*>(ol)[i] = l;
}

// ---------------- per-layer weight folding ---------------------------------
// M1 = Ws + Wu*Wm_dst, M2 = Wu*Wm_src, c1 = bs+bu+Wu*bm, c0 = bs+bu
// M1/M2 pre-split into bf16 hi/lo pairs, stored [o][k] row-major
// (MFMA B-frag = one contiguous 16B read). WsT fp32 [k][o] for bnd/fixup.
__global__ void k_fold(const float* __restrict__ Wm, const float* __restrict__ bm,
                       const float* __restrict__ Ws, const float* __restrict__ bs,
                       const float* __restrict__ Wu, const float* __restrict__ bu,
                       int d, int so,
                       ushort* __restrict__ M1h, ushort* __restrict__ M1l,
                       ushort* __restrict__ M2h, ushort* __restrict__ M2l,
                       float* __restrict__ WsT, float* __restrict__ c1,
                       float* __restrict__ c0) {
  int idx = blockIdx.x * 256 + threadIdx.x;
  if (idx < d * so) {
    int o = idx % so, k = idx / so;
    const float* wu = Wu + o * 128;
    float s1 = 0.f, s2 = 0.f;
    int tw = 2 * d;
    for (int j = 0; j < 128; ++j) {
      float u = wu[j];
      s1 = fmaf(u, Wm[j * tw + d + k], s1);
      s2 = fmaf(u, Wm[j * tw + k], s2);
    }
    float wsv = Ws[o * d + k];
    float m1 = wsv + s1;
    ushort h1 = f2b(m1);
    M1h[o * d + k] = h1;
    M1l[o * d + k] = f2b(m1 - b2f(h1));
    ushort h2 = f2b(s2);
    M2h[o * d + k] = h2;
    M2l[o * d + k] = f2b(s2 - b2f(h2));
    WsT[k * so + o] = wsv;
  }
  if (idx < so) {
    float s = 0.f;
    for (int j = 0; j < 128; ++j) s = fmaf(Wu[idx * 128 + j], bm[j], s);
    c1[idx] = bs[idx] + bu[idx] + s;
    c0[idx] = bs[idx] + bu[idx];
  }
}

// ---------------- scatter-mean of bf16-hi features (wave per node) ---------
// fp32 accumulate; result split to bf16 hi/lo for the MFMA A-path.
template <int D>
__global__ void k_agg(const ushort* __restrict__ Xh, const ushort* __restrict__ BVh,
                      const int* __restrict__ csr, const int* __restrict__ offs,
                      ushort* __restrict__ Smh, ushort* __restrict__ Sml) {
  int v = blockIdx.x * 4 + (threadIdx.x >> 6);
  if (v >= N_I) return;
  int lane = threadIdx.x & 63;
  int o0 = offs[v], o1 = offs[v + 1];
  float a0 = 0.f, a1 = 0.f, b0 = 0.f, b1 = 0.f;
  int p = o0;
  for (; p + 1 < o1; p += 2) {
    int s0 = csr[p], s1 = csr[p + 1];  // wave-uniform
    const ushort* f0 = (s0 < N_I) ? (Xh + (size_t)s0 * D) : (BVh + (size_t)(s0 - N_I) * D);
    const ushort* f1 = (s1 < N_I) ? (Xh + (size_t)s1 * D) : (BVh + (size_t)(s1 - N_I) * D);
    if (D == 128) {
      uint u0 = *reinterpret_cast<const uint*>(f0 + lane * 2);
      uint u1 = *reinterpret_cast<const uint*>(f1 + lane * 2);
      a0 += __uint_as_float(u0 << 16);
      a1 += __uint_as_float(u0 & 0xffff0000u);
      b0 += __uint_as_float(u1 << 16);
      b1 += __uint_as_float(u1 & 0xffff0000u);
    } else {
      a0 += b2f(f0[lane]);
      b0 += b2f(f1[lane]);
    }
  }
  if (p < o1) {
    int s0 = csr[p];
    const ushort* f0 = (s0 < N_I) ? (Xh + (size_t)s0 * D) : (BVh + (size_t)(s0 - N_I) * D);
    if (D == 128) {
      uint u0 = *reinterpret_cast<const uint*>(f0 + lane * 2);
      a0 += __uint_as_float(u0 << 16);
      a1 += __uint_as_float(u0 & 0xffff0000u);
    } else {
      a0 += b2f(f0[lane]);
    }
  }
  float inv = 1.0f / (float)max(o1 - o0, 1);
  float m0 = (a0 + b0) * inv;
  if (D == 128) {
    float m1 = (a1 + b1) * inv;
    ushort h0 = f2b(m0), h1 = f2b(m1);
    ushort l0 = f2b(m0 - b2f(h0)), l1 = f2b(m1 - b2f(h1));
    reinterpret_cast<uint*>(Smh + (size_t)v * D)[lane] = (uint)h0 | ((uint)h1 << 16);
    reinterpret_cast<uint*>(Sml + (size_t)v * D)[lane] = (uint)l0 | ((uint)l1 << 16);
  } else {
    ushort h0 = f2b(m0);
    Smh[(size_t)v * D + lane] = h0;
    Sml[(size_t)v * D + lane] = f2b(m0 - b2f(h0));
  }
}

// ---------------- node update GEMM: Y = act(X*M1^T + Sm*M2^T + c1) ---------
// One wave per 32-row tile, split-bf16 (hi+lo) operands for ~fp32 accuracy:
//   acc += Ah*Wh + Al*Wh + Ah*Wl   (Al*Wl ~2^-18, dropped)
// mfma_f32_32x32x16_bf16 layout:
//   A: row = lane&31, k = (lane>>5)*8 + e ;  B: col = lane&31, same k
//   C/D: col = lane&31, row = (r&3) + 8*(r>>2) + 4*(lane>>5)   [m74/m101]
// ACT: softplus + split-bf16 out (Yh/Yl). !ACT: raw fp32 out (Yf).
template <int D, int SO, bool ACT>
__global__ __launch_bounds__(64) void k_mm(
    const ushort* __restrict__ Xh, const ushort* __restrict__ Xl,
    const ushort* __restrict__ Sh, const ushort* __restrict__ Sl,
    const ushort* __restrict__ M1h, const ushort* __restrict__ M1l,
    const ushort* __restrict__ M2h, const ushort* __restrict__ M2l,
    const float* __restrict__ c1, ushort* __restrict__ Yh,
    ushort* __restrict__ Yl, float* __restrict__ Yf) {
  constexpr int NT = SO / 32;
  int tile = blockIdx.x;
  int lane = threadIdx.x;
  int l31 = lane & 31, hi5 = lane >> 5;
  int row = tile * 32 + l31;
  int rrow = min(row, N_I - 1);  // clamp loads; stores are bounds-checked
  f32x16 acc[NT];
#pragma unroll
  for (int ct = 0; ct < NT; ++ct) {
    float b = c1[ct * 32 + l31];
#pragma unroll
    for (int r = 0; r < 16; ++r) acc[ct][r] = b;
  }
#pragma unroll
  for (int src = 0; src < 2; ++src) {
    const ushort* Ah = src == 0 ? Xh : Sh;
    const ushort* Al = src == 0 ? Xl : Sl;
    const ushort* Wh = src == 0 ? M1h : M2h;
    const ushort* Wl = src == 0 ? M1l : M2l;
#pragma unroll
    for (int ks = 0; ks < D / 16; ++ks) {
      size_t ao = (size_t)rrow * D + ks * 16 + hi5 * 8;
      short8 ah = *reinterpret_cast<const short8*>(Ah + ao);
      short8 al = *reinterpret_cast<const short8*>(Al + ao);
#pragma unroll
      for (int ct = 0; ct < NT; ++ct) {
        size_t wo = (size_t)(ct * 32 + l31) * D + ks * 16 + hi5 * 8;
        short8 wh = *reinterpret_cast<const short8*>(Wh + wo);
        short8 wl = *reinterpret_cast<const short8*>(Wl + wo);
        acc[ct] = __builtin_amdgcn_mfma_f32_32x32x16_bf16(ah, wh, acc[ct], 0, 0, 0);
        acc[ct] = __builtin_amdgcn_mfma_f32_32x32x16_bf16(al, wh, acc[ct], 0, 0, 0);
        acc[ct] = __builtin_amdgcn_mfma_f32_32x32x16_bf16(ah, wl, acc[ct], 0, 0, 0);
      }
    }
  }
#pragma unroll
  for (int ct = 0; ct < NT; ++ct) {
    int col = ct * 32 + l31;
#pragma unroll
    for (int r = 0; r < 16; ++r) {
      int rit = (r & 3) + 8 * (r >> 2) + 4 * hi5;
      int grow = tile * 32 + rit;
      if (grow < N_I) {
        float v = acc[ct][r];
        if (ACT) {
          v = softplusf(v);
          ushort h = f2b(v);
          Yh[(size_t)grow * SO + col] = h;
          Yl[(size_t)grow * SO + col] = f2b(v - b2f(h));
        } else {
          Yf[(size_t)grow * SO + col] = v;
        }
      }
    }
  }
}

// ---------------- deg==0 fixup: y = act(Ws*x + c0) -------------------------
template <int D, int SO, bool ACT>
__global__ void k_fix(const int* __restrict__ zcnt, const int* __restrict__ zlist,
                      const ushort* __restrict__ Xh, const ushort* __restrict__ Xl,
                      const float* __restrict__ WsT, const float* __restrict__ c0,
                      ushort* __restrict__ Yh, ushort* __restrict__ Yl,
                      float* __restrict__ Yf) {
  int nz = zcnt[0];
  int o = threadIdx.x;
  if (o >= SO) return;
  for (int i = 0; i < nz; ++i) {
    int v = zlist[i];
    float s = c0[o];
    for (int k = 0; k < D; ++k) {
      float x = b2f(Xh[(size_t)v * D + k]) + b2f(Xl[(size_t)v * D + k]);
      s = fmaf(WsT[k * SO + o], x, s);
    }
    if (ACT) {
      s = softplusf(s);
      ushort h = f2b(s);
      Yh[(size_t)v * SO + o] = h;
      Yl[(size_t)v * SO + o] = f2b(s - b2f(h));
    } else {
      Yf[(size_t)v * SO + o] = s;
    }
  }
}

// ---------------- boundary update: bv' = softplus(Ws*bv + bs) --------------
// fp32 in/out (for next k_bnd) + bf16-hi copy (for next k_agg gather).
template <int D, int SO>
__global__ void k_bnd(const float* __restrict__ BVin, const float* __restrict__ WsT,
                      const float* __restrict__ bs, float* __restrict__ out,
                      ushort* __restrict__ outh) {
  constexpr int TPN = SO / 4;
  constexpr int NPB = 256 / TPN;
  __shared__ float lx[NPB * D];
  int t = threadIdx.x;
  int base = blockIdx.x * NPB;
  for (int i = t; i < NPB * D; i += 256) lx[i] = BVin[(size_t)base * D + i];
  __syncthreads();
  int g = t / TPN;
  int o = (t % TPN) * 4;
  int v = base + g;
  float4 acc = make_float4(bs[o], bs[o + 1], bs[o + 2], bs[o + 3]);
  const float* xr = lx + g * D;
  const float4* W4 = reinterpret_cast<const float4*>(WsT);
#pragma unroll 8
  for (int k = 0; k < D; ++k) {
    float4 w = W4[k * (SO / 4) + (o >> 2)];
    float xv = xr[k];
    acc.x = fmaf(xv, w.x, acc.x);
    acc.y = fmaf(xv, w.y, acc.y);
    acc.z = fmaf(xv, w.z, acc.z);
    acc.w = fmaf(xv, w.w, acc.w);
  }
  float4 ov;
  ov.x = softplusf(acc.x);
  ov.y = softplusf(acc.y);
  ov.z = softplusf(acc.z);
  ov.w = softplusf(acc.w);
  reinterpret_cast<float4*>(out + (size_t)v * SO)[o >> 2] = ov;
  ushort4 oh;
  oh.x = f2b(ov.x); oh.y = f2b(ov.y); oh.z = f2b(ov.z); oh.w = f2b(ov.w);
  reinterpret_cast<ushort4*>(outh + (size_t)v * SO)[o >> 2] = oh;
}

extern "C" void kernel_launch(void* const* d_in, const int* in_sizes, int n_in,
                              void* d_out, int out_size, void* d_ws, size_t ws_size,
                              hipStream_t stream) {
  const float* t_in = (const float*)d_in[0];
  const float* x_int = (const float*)d_in[1];
  const float* bvals = (const float*)d_in[2];
  const int* ei = (const int*)d_in[3];
  const int* eb = (const int*)d_in[4];
  const float* ts = (const float*)d_in[5];
  const float* W[4][6];
  for (int l = 0; l < 4; ++l)
    for (int j = 0; j < 6; ++j) W[l][j] = (const float*)d_in[6 + l * 6 + j];
  // j: 0=Wm 1=bm 2=Ws 3=bs 4=Wu 5=bu

  char* ws = (char*)d_ws;
  size_t off = 0;
  auto alloc = [&](size_t bytes) {
    void* p = ws + off;
    off = (off + bytes + 255) & ~(size_t)255;
    return p;
  };
  int* cnt = (int*)alloc(N_I * 4);
  int* offs = (int*)alloc((N_I + 1) * 4);
  int* cursor = (int*)alloc(N_I * 4);
  int* csr = (int*)alloc((size_t)E_T * 4);
  int* bsum = (int*)alloc(64 * 4);
  int* zcnt = (int*)alloc(4);
  int* zlist = (int*)alloc(N_I * 4);
  // Activation ping-pong, split bf16 hi/lo. bufA holds layer-1 input (64-dim
  // layout) then is overwritten by layer-2 output (128-dim); bufB holds
  // layer-1/3 outputs.
  ushort* Ah = (ushort*)alloc((size_t)N_I * 128 * 2);
  ushort* Al = (ushort*)alloc((size_t)N_I * 128 * 2);
  ushort* Bh = (ushort*)alloc((size_t)N_I * 128 * 2);
  ushort* Bl = (ushort*)alloc((size_t)N_I * 128 * 2);
  ushort* Smh = (ushort*)alloc((size_t)N_I * 128 * 2);
  ushort* Sml = (ushort*)alloc((size_t)N_I * 128 * 2);
  float* bv1 = (float*)alloc((size_t)N_B * 64 * 4);
  float* bv2 = (float*)alloc((size_t)N_B * 128 * 4);
  float* bv3 = (float*)alloc((size_t)N_B * 128 * 4);
  float* bv4 = (float*)alloc((size_t)N_B * 128 * 4);
  ushort* bvh1 = (ushort*)alloc((size_t)N_B * 64 * 2);
  ushort* bvh2 = (ushort*)alloc((size_t)N_B * 128 * 2);
  ushort* bvh3 = (ushort*)alloc((size_t)N_B * 128 * 2);
  ushort* bvh4 = (ushort*)alloc((size_t)N_B * 128 * 2);
  ushort *M1h[4], *M1l[4], *M2h[4], *M2l[4];
  float *WsT[4], *c1[4], *c0[4];
  for (int l = 0; l < 4; ++l) {
    M1h[l] = (ushort*)alloc(16384 * 2);
    M1l[l] = (ushort*)alloc(16384 * 2);
    M2h[l] = (ushort*)alloc(16384 * 2);
    M2l[l] = (ushort*)alloc(16384 * 2);
    WsT[l] = (float*)alloc(16384 * 4);
    c1[l] = (float*)alloc(128 * 4);
    c0[l] = (float*)alloc(128 * 4);
  }
  (void)ws_size; (void)in_sizes; (void)n_in; (void)out_size;

  hipMemsetAsync(cnt, 0, N_I * 4, stream);
  hipMemsetAsync(zcnt, 0, 4, stream);
  int egrid = (E_T + 255) / 256;
  k_count<<<egrid, 256, 0, stream>>>(ei, eb, cnt);
  k_scan1<<<SCAN_NB, 256, 0, stream>>>(cnt, cursor /*tmp*/, bsum);
  k_scan2<<<1, 64, 0, stream>>>(bsum);
  k_scan3<<<SCAN_NB, 256, 0, stream>>>(cursor, bsum, offs, cursor);
  k_fill<<<egrid, 256, 0, stream>>>(ei, eb, cursor, csr);
  k_zlist<<<(N_I + 255) / 256, 256, 0, stream>>>(offs, zcnt, zlist);
  k_bvt<<<(N_B * 64 + 255) / 256, 256, 0, stream>>>(t_in, ts, bvals, bv1, bvh1);
  k_cvt<<<(N_I * 64 / 4 + 255) / 256, 256, 0, stream>>>(x_int, Ah, Al, N_I * 64 / 4);

  int ds[4] = {64, 128, 128, 128};
  int sos[4] = {128, 128, 128, 64};
  for (int l = 0; l < 4; ++l) {
    int tot = ds[l] * sos[l];
    k_fold<<<(tot + 255) / 256, 256, 0, stream>>>(
        W[l][0], W[l][1], W[l][2], W[l][3], W[l][4], W[l][5], ds[l], sos[l],
        M1h[l], M1l[l], M2h[l], M2l[l], WsT[l], c1[l], c0[l]);
  }

  constexpr int MM_GRID = (N_I + 31) / 32;  // 1563 single-wave blocks
  constexpr int BND_GRID = N_B / 8;         // NPB==8 for all layers -> 250

  // Layer 1: D=64 -> 128   (reads bufA as [N_I][64], writes bufB [N_I][128])
  k_agg<64><<<N_I / 4, 256, 0, stream>>>(Ah, bvh1, csr, offs, Smh, Sml);
  k_mm<64, 128, true><<<MM_GRID, 64, 0, stream>>>(Ah, Al, Smh, Sml, M1h[0], M1l[0],
                                                  M2h[0], M2l[0], c1[0], Bh, Bl,
                                                  nullptr);
  k_fix<64, 128, true><<<1, 128, 0, stream>>>(zcnt, zlist, Ah, Al, WsT[0], c0[0],
                                              Bh, Bl, nullptr);
  k_bnd<64, 128><<<BND_GRID, 256, 0, stream>>>(bv1, WsT[0], W[0][3], bv2, bvh2);

  // Layer 2: 128 -> 128    (reads bufB, overwrites bufA)
  k_agg<128><<<N_I / 4, 256, 0, stream>>>(Bh, bvh2, csr, offs, Smh, Sml);
  k_mm<128, 128, true><<<MM_GRID, 64, 0, stream>>>(Bh, Bl, Smh, Sml, M1h[1], M1l[1],
                                                   M2h[1], M2l[1], c1[1], Ah, Al,
                                                   nullptr);
  k_fix<128, 128, true><<<1, 128, 0, stream>>>(zcnt, zlist, Bh, Bl, WsT[1], c0[1],
                                               Ah, Al, nullptr);
  k_bnd<128, 128><<<BND_GRID, 256, 0, stream>>>(bv2, WsT[1], W[1][3], bv3, bvh3);

  // Layer 3: 128 -> 128    (reads bufA, writes bufB)
  k_agg<128><<<N_I / 4, 256, 0, stream>>>(Ah, bvh3, csr, offs, Smh, Sml);
  k_mm<128, 128, true><<<MM_GRID, 64, 0, stream>>>(Ah, Al, Smh, Sml, M1h[2], M1l[2],
                                                   M2h[2], M2l[2], c1[2], Bh, Bl,
                                                   nullptr);
  k_fix<128, 128, true><<<1, 128, 0, stream>>>(zcnt, zlist, Ah, Al, WsT[2], c0[2],
                                               Bh, Bl, nullptr);
  k_bnd<128, 128><<<BND_GRID, 256, 0, stream>>>(bv3, WsT[2], W[2][3], bv4, bvh4);

  // Layer 4: 128 -> 64, no activation, fp32 straight to d_out
  k_agg<128><<<N_I / 4, 256, 0, stream>>>(Bh, bvh4, csr, offs, Smh, Sml);
  k_mm<128, 64, false><<<MM_GRID, 64, 0, stream>>>(Bh, Bl, Smh, Sml, M1h[3], M1l[3],
                                                   M2h[3], M2l[3], c1[3], nullptr,
                                                   nullptr, (float*)d_out);
  k_fix<128, 64, false><<<1, 128, 0, stream>>>(zcnt, zlist, Bh, Bl, WsT[3], c0[3],
                                               nullptr, nullptr, (float*)d_out);
}

// Round 5
// 564.474 us; speedup vs baseline: 1.8939x; 1.1277x over previous
//
#include <hip/hip_runtime.h>
#include <hip/hip_bf16.h>
#include <math.h>

// Problem constants (fixed by the reference).
constexpr int N_I = 50000;   // interior nodes
constexpr int N_B = 2000;    // boundary nodes
constexpr int E_I = 800000;  // interior edges
constexpr int E_B = 16000;   // boundary edges
constexpr int E_T = E_I + E_B;
constexpr int SCAN_NB = (N_I + 1023) / 1024;  // 49
constexpr int NTILES = (N_I + 31) / 32;       // 1563 row-tiles
constexpr int MM_GRID = 512;                  // 2 blocks/CU, grid-stride tiles

using short8 = __attribute__((ext_vector_type(8))) short;
using f32x16 = __attribute__((ext_vector_type(16))) float;

__device__ __forceinline__ float softplusf(float x) {
  return fmaxf(x, 0.0f) + log1pf(expf(-fabsf(x)));
}
__device__ __forceinline__ float b2f(ushort u) {
  return __uint_as_float((uint)u << 16);
}
__device__ __forceinline__ ushort f2b(float f) {
  __hip_bfloat16 h = __float2bfloat16(f);  // RNE
  return *reinterpret_cast<ushort*>(&h);
}

// ---------------- CSR build (once per call, reused by all 4 layers) --------
__global__ void k_count(const int* __restrict__ ei, const int* __restrict__ eb,
                        int* __restrict__ cnt) {
  int e = blockIdx.x * 256 + threadIdx.x;
  if (e >= E_T) return;
  int dst = (e < E_I) ? ei[E_I + e] : eb[E_B + (e - E_I)];
  atomicAdd(&cnt[dst], 1);
}

__global__ void k_scan1(const int* __restrict__ cnt, int* __restrict__ tmp,
                        int* __restrict__ bsum) {
  int t = threadIdx.x;
  int lane = t & 63, wid = t >> 6;
  int base = blockIdx.x * 1024 + t * 4;
  int c[4];
#pragma unroll
  for (int i = 0; i < 4; ++i) c[i] = (base + i < N_I) ? cnt[base + i] : 0;
  int s = c[0] + c[1] + c[2] + c[3];
  int inc = s;
#pragma unroll
  for (int d = 1; d < 64; d <<= 1) {
    int u = __shfl_up(inc, d, 64);
    if (lane >= d) inc += u;
  }
  __shared__ int wtot[4];
  if (lane == 63) wtot[wid] = inc;
  __syncthreads();
  int woff = 0;
  for (int i = 0; i < wid; ++i) woff += wtot[i];
  int excl = woff + inc - s;
  int run = excl;
#pragma unroll
  for (int i = 0; i < 4; ++i) {
    if (base + i < N_I) tmp[base + i] = run;
    run += c[i];
  }
  if (t == 255) bsum[blockIdx.x] = woff + inc;
}

__global__ void k_scan2(int* bsum) {
  int t = threadIdx.x;  // 64 threads, 1 wave
  int v = (t < SCAN_NB) ? bsum[t] : 0;
  int inc = v;
#pragma unroll
  for (int d = 1; d < 64; d <<= 1) {
    int u = __shfl_up(inc, d, 64);
    if (t >= d) inc += u;
  }
  if (t < SCAN_NB) bsum[t] = inc - v;  // exclusive
}

// NOTE: tmp and cursor may alias (same-thread read-then-write) -> no restrict.
__global__ void k_scan3(const int* tmp, const int* bsum, int* offs, int* cursor) {
  int t = threadIdx.x;
  int base = blockIdx.x * 1024 + t * 4;
  int add = bsum[blockIdx.x];
#pragma unroll
  for (int i = 0; i < 4; ++i) {
    int idx = base + i;
    if (idx < N_I) {
      int v = tmp[idx] + add;
      offs[idx] = v;
      cursor[idx] = v;
    }
  }
  if (blockIdx.x == 0 && t == 0) offs[N_I] = E_T;
}

__global__ void k_fill(const int* __restrict__ ei, const int* __restrict__ eb,
                       int* __restrict__ cursor, int* __restrict__ csr) {
  int e = blockIdx.x * 256 + threadIdx.x;
  if (e >= E_T) return;
  int src, dst;
  if (e < E_I) {
    src = ei[e];
    dst = ei[E_I + e];
  } else {
    int j = e - E_I;
    src = eb[j];        // already >= N_I (global boundary id)
    dst = eb[E_B + j];
  }
  int pos = atomicAdd(&cursor[dst], 1);
  csr[pos] = src;
}

__global__ void k_zlist(const int* __restrict__ offs, int* __restrict__ zcnt,
                        int* __restrict__ zlist) {
  int v = blockIdx.x * 256 + threadIdx.x;
  if (v >= N_I) return;
  if (offs[v + 1] == offs[v]) {
    int p = atomicAdd(zcnt, 1);
    zlist[p] = v;
  }
}

// ---------------- boundary-value interpolation at t ------------------------
__global__ void k_bvt(const float* __restrict__ tptr, const float* __restrict__ ts,
                      const float* __restrict__ BV, float* __restrict__ out,
                      ushort* __restrict__ outh) {
  int idx = blockIdx.x * 256 + threadIdx.x;
  if (idx >= N_B * 64) return;
  float tv = tptr[0];
  int pos = 0;
#pragma unroll
  for (int i = 0; i < 8; ++i) pos += (ts[i] < tv) ? 1 : 0;  // searchsorted left
  int il = max(pos - 1, 0), ir = min(pos, 7);
  float tl = ts[il], tr = ts[ir];
  float vl = BV[il * (N_B * 64) + idx];
  float vr = BV[ir * (N_B * 64) + idx];
  bool eq = (tl == tr);
  float denom = eq ? 1.0f : (tr - tl);
  float v = eq ? vl : vl + (tv - tl) * (vr - vl) / denom;
  out[idx] = v;
  outh[idx] = f2b(v);
}

// ---------------- x_int fp32 -> split bf16 hi/lo ---------------------------
__global__ void k_cvt(const float* __restrict__ in, ushort* __restrict__ oh,
                      ushort* __restrict__ ol, int n4) {
  int i = blockIdx.x * 256 + threadIdx.x;
  if (i >= n4) return;
  float4 v = reinterpret_cast<const float4*>(in)[i];
  ushort4 h, l;
  h.x = f2b(v.x); l.x = f2b(v.x - b2f(h.x));
  h.y = f2b(v.y); l.y = f2b(v.y - b2f(h.y));
  h.z = f2b(v.z); l.z = f2b(v.z - b2f(h.z));
  h.w = f2b(v.w); l.w = f2b(v.w - b2f(h.w));
  reinterpret_cast<ushort4*>(oh)[i] = h;
  reinterpret_cast<ushort4*>(ol)[i] = l;
}

// ---------------- per-layer weight folding ---------------------------------
// M1 = Ws + Wu*Wm_dst, M2 = Wu*Wm_src, c1 = bs+bu+Wu*bm, c0 = bs+bu
// M1/M2 pre-split into bf16 hi/lo pairs, stored [o][k] row-major
// (MFMA B-frag = one contiguous 16B read). WsT fp32 [k][o] for bnd/fixup.
__global__ void k_fold(const float* __restrict__ Wm, const float* __restrict__ bm,
                       const float* __restrict__ Ws, const float* __restrict__ bs,
                       const float* __restrict__ Wu, const float* __restrict__ bu,
                       int d, int so,
                       ushort* __restrict__ M1h, ushort* __restrict__ M1l,
                       ushort* __restrict__ M2h, ushort* __restrict__ M2l,
                       float* __restrict__ WsT, float* __restrict__ c1,
                       float* __restrict__ c0) {
  int idx = blockIdx.x * 256 + threadIdx.x;
  if (idx < d * so) {
    int o = idx % so, k = idx / so;
    const float* wu = Wu + o * 128;
    float s1 = 0.f, s2 = 0.f;
    int tw = 2 * d;
    for (int j = 0; j < 128; ++j) {
      float u = wu[j];
      s1 = fmaf(u, Wm[j * tw + d + k], s1);
      s2 = fmaf(u, Wm[j * tw + k], s2);
    }
    float wsv = Ws[o * d + k];
    float m1 = wsv + s1;
    ushort h1 = f2b(m1);
    M1h[o * d + k] = h1;
    M1l[o * d + k] = f2b(m1 - b2f(h1));
    ushort h2 = f2b(s2);
    M2h[o * d + k] = h2;
    M2l[o * d + k] = f2b(s2 - b2f(h2));
    WsT[k * so + o] = wsv;
  }
  if (idx < so) {
    float s = 0.f;
    for (int j = 0; j < 128; ++j) s = fmaf(Wu[idx * 128 + j], bm[j], s);
    c1[idx] = bs[idx] + bu[idx] + s;
    c0[idx] = bs[idx] + bu[idx];
  }
}

// ---------------- scatter-mean of bf16-hi features (wave per node) ---------
// fp32 accumulate; result split to bf16 hi/lo for the MFMA A-path.
template <int D>
__global__ void k_agg(const ushort* __restrict__ Xh, const ushort* __restrict__ BVh,
                      const int* __restrict__ csr, const int* __restrict__ offs,
                      ushort* __restrict__ Smh, ushort* __restrict__ Sml) {
  int v = blockIdx.x * 4 + (threadIdx.x >> 6);
  if (v >= N_I) return;
  int lane = threadIdx.x & 63;
  int o0 = offs[v], o1 = offs[v + 1];
  float a0 = 0.f, a1 = 0.f, b0 = 0.f, b1 = 0.f;
  int p = o0;
  for (; p + 1 < o1; p += 2) {
    int s0 = csr[p], s1 = csr[p + 1];  // wave-uniform
    const ushort* f0 = (s0 < N_I) ? (Xh + (size_t)s0 * D) : (BVh + (size_t)(s0 - N_I) * D);
    const ushort* f1 = (s1 < N_I) ? (Xh + (size_t)s1 * D) : (BVh + (size_t)(s1 - N_I) * D);
    if (D == 128) {
      uint u0 = *reinterpret_cast<const uint*>(f0 + lane * 2);
      uint u1 = *reinterpret_cast<const uint*>(f1 + lane * 2);
      a0 += __uint_as_float(u0 << 16);
      a1 += __uint_as_float(u0 & 0xffff0000u);
      b0 += __uint_as_float(u1 << 16);
      b1 += __uint_as_float(u1 & 0xffff0000u);
    } else {
      a0 += b2f(f0[lane]);
      b0 += b2f(f1[lane]);
    }
  }
  if (p < o1) {
    int s0 = csr[p];
    const ushort* f0 = (s0 < N_I) ? (Xh + (size_t)s0 * D) : (BVh + (size_t)(s0 - N_I) * D);
    if (D == 128) {
      uint u0 = *reinterpret_cast<const uint*>(f0 + lane * 2);
      a0 += __uint_as_float(u0 << 16);
      a1 += __uint_as_float(u0 & 0xffff0000u);
    } else {
      a0 += b2f(f0[lane]);
    }
  }
  float inv = 1.0f / (float)max(o1 - o0, 1);
  float m0 = (a0 + b0) * inv;
  if (D == 128) {
    float m1 = (a1 + b1) * inv;
    ushort h0 = f2b(m0), h1 = f2b(m1);
    ushort l0 = f2b(m0 - b2f(h0)), l1 = f2b(m1 - b2f(h1));
    reinterpret_cast<uint*>(Smh + (size_t)v * D)[lane] = (uint)h0 | ((uint)h1 << 16);
    reinterpret_cast<uint*>(Sml + (size_t)v * D)[lane] = (uint)l0 | ((uint)l1 << 16);
  } else {
    ushort h0 = f2b(m0);
    Smh[(size_t)v * D + lane] = h0;
    Sml[(size_t)v * D + lane] = f2b(m0 - b2f(h0));
  }
}

// ---------------- node update GEMM: Y = act(X*M1^T + Sm*M2^T + c1) ---------
// One wave OWNS one 32-col tile (ct = wave id); its B-fragments (hi+lo, both
// sources) live in VGPRs (loaded once), and the wave grid-strides over 32-row
// tiles. Split-bf16: acc += Ah*Wh + Al*Wh + Ah*Wl  (Al*Wl ~2^-18, dropped).
// Two accumulator chains (X-path with bias, Sm-path zero) summed at store.
// mfma_f32_32x32x16_bf16 layout:
//   A: row = lane&31, k = (lane>>5)*8 + e ;  B: col = lane&31, same k
//   C/D: col = lane&31, row = (r&3) + 8*(r>>2) + 4*(lane>>5)   [m74/m101]
template <int D, int SO, bool ACT>
__global__ __launch_bounds__(64 * (SO / 32), 2) void k_mm(
    const ushort* __restrict__ Xh, const ushort* __restrict__ Xl,
    const ushort* __restrict__ Sh, const ushort* __restrict__ Sl,
    const ushort* __restrict__ M1h, const ushort* __restrict__ M1l,
    const ushort* __restrict__ M2h, const ushort* __restrict__ M2l,
    const float* __restrict__ c1, ushort* __restrict__ Yh,
    ushort* __restrict__ Yl, float* __restrict__ Yf) {
  constexpr int KS = D / 16;
  int wid = threadIdx.x >> 6;  // this wave's col-tile
  int lane = threadIdx.x & 63;
  int l31 = lane & 31, hi5 = lane >> 5;
  int col = wid * 32 + l31;
  size_t wbase = (size_t)col * D + hi5 * 8;
  // Resident weights: 4*KS fragments (KS<=8 -> <=128 VGPRs).
  short8 w1h[KS], w1l[KS], w2h[KS], w2l[KS];
#pragma unroll
  for (int ks = 0; ks < KS; ++ks) {
    w1h[ks] = *reinterpret_cast<const short8*>(M1h + wbase + ks * 16);
    w1l[ks] = *reinterpret_cast<const short8*>(M1l + wbase + ks * 16);
    w2h[ks] = *reinterpret_cast<const short8*>(M2h + wbase + ks * 16);
    w2l[ks] = *reinterpret_cast<const short8*>(M2l + wbase + ks * 16);
  }
  float bias = c1[col];
  for (int rt = blockIdx.x; rt < NTILES; rt += MM_GRID) {
    int row = rt * 32 + l31;
    int rrow = min(row, N_I - 1);  // clamp loads; stores are bounds-checked
    size_t abase = (size_t)rrow * D + hi5 * 8;
    f32x16 accA, accB;
#pragma unroll
    for (int r = 0; r < 16; ++r) {
      accA[r] = bias;
      accB[r] = 0.0f;
    }
#pragma unroll
    for (int ks = 0; ks < KS; ++ks) {
      short8 xh = *reinterpret_cast<const short8*>(Xh + abase + ks * 16);
      short8 xl = *reinterpret_cast<const short8*>(Xl + abase + ks * 16);
      short8 sh = *reinterpret_cast<const short8*>(Sh + abase + ks * 16);
      short8 sl = *reinterpret_cast<const short8*>(Sl + abase + ks * 16);
      accA = __builtin_amdgcn_mfma_f32_32x32x16_bf16(xh, w1h[ks], accA, 0, 0, 0);
      accB = __builtin_amdgcn_mfma_f32_32x32x16_bf16(sh, w2h[ks], accB, 0, 0, 0);
      accA = __builtin_amdgcn_mfma_f32_32x32x16_bf16(xl, w1h[ks], accA, 0, 0, 0);
      accB = __builtin_amdgcn_mfma_f32_32x32x16_bf16(sl, w2h[ks], accB, 0, 0, 0);
      accA = __builtin_amdgcn_mfma_f32_32x32x16_bf16(xh, w1l[ks], accA, 0, 0, 0);
      accB = __builtin_amdgcn_mfma_f32_32x32x16_bf16(sh, w2l[ks], accB, 0, 0, 0);
    }
#pragma unroll
    for (int r = 0; r < 16; ++r) {
      int rit = (r & 3) + 8 * (r >> 2) + 4 * hi5;
      int grow = rt * 32 + rit;
      if (grow < N_I) {
        float v = accA[r] + accB[r];
        if (ACT) {
          v = softplusf(v);
          ushort h = f2b(v);
          Yh[(size_t)grow * SO + col] = h;
          Yl[(size_t)grow * SO + col] = f2b(v - b2f(h));
        } else {
          Yf[(size_t)grow * SO + col] = v;
        }
      }
    }
  }
}

// ---------------- deg==0 fixup: y = act(Ws*x + c0) -------------------------
template <int D, int SO, bool ACT>
__global__ void k_fix(const int* __restrict__ zcnt, const int* __restrict__ zlist,
                      const ushort* __restrict__ Xh, const ushort* __restrict__ Xl,
                      const float* __restrict__ WsT, const float* __restrict__ c0,
                      ushort* __restrict__ Yh, ushort* __restrict__ Yl,
                      float* __restrict__ Yf) {
  int nz = zcnt[0];
  int o = threadIdx.x;
  if (o >= SO) return;
  for (int i = 0; i < nz; ++i) {
    int v = zlist[i];
    float s = c0[o];
    for (int k = 0; k < D; ++k) {
      float x = b2f(Xh[(size_t)v * D + k]) + b2f(Xl[(size_t)v * D + k]);
      s = fmaf(WsT[k * SO + o], x, s);
    }
    if (ACT) {
      s = softplusf(s);
      ushort h = f2b(s);
      Yh[(size_t)v * SO + o] = h;
      Yl[(size_t)v * SO + o] = f2b(s - b2f(h));
    } else {
      Yf[(size_t)v * SO + o] = s;
    }
  }
}

// ---------------- boundary update: bv' = softplus(Ws*bv + bs) --------------
// fp32 in/out (for next k_bnd) + bf16-hi copy (for next k_agg gather).
template <int D, int SO>
__global__ void k_bnd(const float* __restrict__ BVin, const float* __restrict__ WsT,
                      const float* __restrict__ bs, float* __restrict__ out,
                      ushort* __restrict__ outh) {
  constexpr int TPN = SO / 4;
  constexpr int NPB = 256 / TPN;
  __shared__ float lx[NPB * D];
  int t = threadIdx.x;
  int base = blockIdx.x * NPB;
  for (int i = t; i < NPB * D; i += 256) lx[i] = BVin[(size_t)base * D + i];
  __syncthreads();
  int g = t / TPN;
  int o = (t % TPN) * 4;
  int v = base + g;
  float4 acc = make_float4(bs[o], bs[o + 1], bs[o + 2], bs[o + 3]);
  const float* xr = lx + g * D;
  const float4* W4 = reinterpret_cast<const float4*>(WsT);
#pragma unroll 8
  for (int k = 0; k < D; ++k) {
    float4 w = W4[k * (SO / 4) + (o >> 2)];
    float xv = xr[k];
    acc.x = fmaf(xv, w.x, acc.x);
    acc.y = fmaf(xv, w.y, acc.y);
    acc.z = fmaf(xv, w.z, acc.z);
    acc.w = fmaf(xv, w.w, acc.w);
  }
  float4 ov;
  ov.x = softplusf(acc.x);
  ov.y = softplusf(acc.y);
  ov.z = softplusf(acc.z);
  ov.w = softplusf(acc.w);
  reinterpret_cast<float4*>(out + (size_t)v * SO)[o >> 2] = ov;
  ushort4 oh;
  oh.x = f2b(ov.x); oh.y = f2b(ov.y); oh.z = f2b(ov.z); oh.w = f2b(ov.w);
  reinterpret_cast<ushort4*>(outh + (size_t)v * SO)[o >> 2] = oh;
}

extern "C" void kernel_launch(void* const* d_in, const int* in_sizes, int n_in,
                              void* d_out, int out_size, void* d_ws, size_t ws_size,
                              hipStream_t stream) {
  const float* t_in = (const float*)d_in[0];
  const float* x_int = (const float*)d_in[1];
  const float* bvals = (const float*)d_in[2];
  const int* ei = (const int*)d_in[3];
  const int* eb = (const int*)d_in[4];
  const float* ts = (const float*)d_in[5];
  const float* W[4][6];
  for (int l = 0; l < 4; ++l)
    for (int j = 0; j < 6; ++j) W[l][j] = (const float*)d_in[6 + l * 6 + j];
  // j: 0=Wm 1=bm 2=Ws 3=bs 4=Wu 5=bu

  char* ws = (char*)d_ws;
  size_t off = 0;
  auto alloc = [&](size_t bytes) {
    void* p = ws + off;
    off = (off + bytes + 255) & ~(size_t)255;
    return p;
  };
  int* cnt = (int*)alloc(N_I * 4);
  int* offs = (int*)alloc((N_I + 1) * 4);
  int* cursor = (int*)alloc(N_I * 4);
  int* csr = (int*)alloc((size_t)E_T * 4);
  int* bsum = (int*)alloc(64 * 4);
  int* zcnt = (int*)alloc(4);
  int* zlist = (int*)alloc(N_I * 4);
  // Activation ping-pong, split bf16 hi/lo.
  ushort* Ah = (ushort*)alloc((size_t)N_I * 128 * 2);
  ushort* Al = (ushort*)alloc((size_t)N_I * 128 * 2);
  ushort* Bh = (ushort*)alloc((size_t)N_I * 128 * 2);
  ushort* Bl = (ushort*)alloc((size_t)N_I * 128 * 2);
  ushort* Smh = (ushort*)alloc((size_t)N_I * 128 * 2);
  ushort* Sml = (ushort*)alloc((size_t)N_I * 128 * 2);
  float* bv1 = (float*)alloc((size_t)N_B * 64 * 4);
  float* bv2 = (float*)alloc((size_t)N_B * 128 * 4);
  float* bv3 = (float*)alloc((size_t)N_B * 128 * 4);
  float* bv4 = (float*)alloc((size_t)N_B * 128 * 4);
  ushort* bvh1 = (ushort*)alloc((size_t)N_B * 64 * 2);
  ushort* bvh2 = (ushort*)alloc((size_t)N_B * 128 * 2);
  ushort* bvh3 = (ushort*)alloc((size_t)N_B * 128 * 2);
  ushort* bvh4 = (ushort*)alloc((size_t)N_B * 128 * 2);
  ushort *M1h[4], *M1l[4], *M2h[4], *M2l[4];
  float *WsT[4], *c1[4], *c0[4];
  for (int l = 0; l < 4; ++l) {
    M1h[l] = (ushort*)alloc(16384 * 2);
    M1l[l] = (ushort*)alloc(16384 * 2);
    M2h[l] = (ushort*)alloc(16384 * 2);
    M2l[l] = (ushort*)alloc(16384 * 2);
    WsT[l] = (float*)alloc(16384 * 4);
    c1[l] = (float*)alloc(128 * 4);
    c0[l] = (float*)alloc(128 * 4);
  }
  (void)ws_size; (void)in_sizes; (void)n_in; (void)out_size;

  hipMemsetAsync(cnt, 0, N_I * 4, stream);
  hipMemsetAsync(zcnt, 0, 4, stream);
  int egrid = (E_T + 255) / 256;
  k_count<<<egrid, 256, 0, stream>>>(ei, eb, cnt);
  k_scan1<<<SCAN_NB, 256, 0, stream>>>(cnt, cursor /*tmp*/, bsum);
  k_scan2<<<1, 64, 0, stream>>>(bsum);
  k_scan3<<<SCAN_NB, 256, 0, stream>>>(cursor, bsum, offs, cursor);
  k_fill<<<egrid, 256, 0, stream>>>(ei, eb, cursor, csr);
  k_zlist<<<(N_I + 255) / 256, 256, 0, stream>>>(offs, zcnt, zlist);
  k_bvt<<<(N_B * 64 + 255) / 256, 256, 0, stream>>>(t_in, ts, bvals, bv1, bvh1);
  k_cvt<<<(N_I * 64 / 4 + 255) / 256, 256, 0, stream>>>(x_int, Ah, Al, N_I * 64 / 4);

  int ds[4] = {64, 128, 128, 128};
  int sos[4] = {128, 128, 128, 64};
  for (int l = 0; l < 4; ++l) {
    int tot = ds[l] * sos[l];
    k_fold<<<(tot + 255) / 256, 256, 0, stream>>>(
        W[l][0], W[l][1], W[l][2], W[l][3], W[l][4], W[l][5], ds[l], sos[l],
        M1h[l], M1l[l], M2h[l], M2l[l], WsT[l], c1[l], c0[l]);
  }

  constexpr int BND_GRID = N_B / 8;  // NPB==8 for all layers -> 250

  // Layer 1: D=64 -> 128   (reads bufA as [N_I][64], writes bufB [N_I][128])
  k_agg<64><<<N_I / 4, 256, 0, stream>>>(Ah, bvh1, csr, offs, Smh, Sml);
  k_mm<64, 128, true><<<MM_GRID, 256, 0, stream>>>(Ah, Al, Smh, Sml, M1h[0], M1l[0],
                                                   M2h[0], M2l[0], c1[0], Bh, Bl,
                                                   nullptr);
  k_fix<64, 128, true><<<1, 128, 0, stream>>>(zcnt, zlist, Ah, Al, WsT[0], c0[0],
                                              Bh, Bl, nullptr);
  k_bnd<64, 128><<<BND_GRID, 256, 0, stream>>>(bv1, WsT[0], W[0][3], bv2, bvh2);

  // Layer 2: 128 -> 128    (reads bufB, overwrites bufA)
  k_agg<128><<<N_I / 4, 256, 0, stream>>>(Bh, bvh2, csr, offs, Smh, Sml);
  k_mm<128, 128, true><<<MM_GRID, 256, 0, stream>>>(Bh, Bl, Smh, Sml, M1h[1], M1l[1],
                                                    M2h[1], M2l[1], c1[1], Ah, Al,
                                                    nullptr);
  k_fix<128, 128, true><<<1, 128, 0, stream>>>(zcnt, zlist, Bh, Bl, WsT[1], c0[1],
                                               Ah, Al, nullptr);
  k_bnd<128, 128><<<BND_GRID, 256, 0, stream>>>(bv2, WsT[1], W[1][3], bv3, bvh3);

  // Layer 3: 128 -> 128    (reads bufA, writes bufB)
  k_agg<128><<<N_I / 4, 256, 0, stream>>>(Ah, bvh3, csr, offs, Smh, Sml);
  k_mm<128, 128, true><<<MM_GRID, 256, 0, stream>>>(Ah, Al, Smh, Sml, M1h[2], M1l[2],
                                                    M2h[2], M2l[2], c1[2], Bh, Bl,
                                                    nullptr);
  k_fix<128, 128, true><<<1, 128, 0, stream>>>(zcnt, zlist, Ah, Al, WsT[2], c0[2],
                                               Bh, Bl, nullptr);
  k_bnd<128, 128><<<BND_GRID, 256, 0, stream>>>(bv3, WsT[2], W[2][3], bv4, bvh4);

  // Layer 4: 128 -> 64, no activation, fp32 straight to d_out
  k_agg<128><<<N_I / 4, 256, 0, stream>>>(Bh, bvh4, csr, offs, Smh, Sml);
  k_mm<128, 64, false><<<MM_GRID, 128, 0, stream>>>(Bh, Bl, Smh, Sml, M1h[3], M1l[3],
                                                    M2h[3], M2l[3], c1[3], nullptr,
                                                    nullptr, (float*)d_out);
  k_fix<128, 64, false><<<1, 128, 0, stream>>>(zcnt, zlist, Bh, Bl, WsT[3], c0[3],
                                               nullptr, nullptr, (float*)d_out);
}

// Round 6
// 491.128 us; speedup vs baseline: 2.1767x; 1.1493x over previous
//
#include <hip/hip_runtime.h>
#include <hip/hip_bf16.h>
#include <math.h>

// Problem constants (fixed by the reference).
constexpr int N_I = 50000;   // interior nodes
constexpr int N_B = 2000;    // boundary nodes
constexpr int E_I = 800000;  // interior edges
constexpr int E_B = 16000;   // boundary edges
constexpr int E_T = E_I + E_B;
constexpr int SCAN_NB = (N_I + 1023) / 1024;  // 49
constexpr int NTILES = (N_I + 31) / 32;       // 1563 row-tiles
constexpr int MM_GRID = 1024;                 // grid-stride; block turnover pipelines

using short8 = __attribute__((ext_vector_type(8))) short;
using f32x16 = __attribute__((ext_vector_type(16))) float;

__device__ __forceinline__ float softplusf(float x) {
  return fmaxf(x, 0.0f) + log1pf(expf(-fabsf(x)));
}
__device__ __forceinline__ float b2f(ushort u) {
  return __uint_as_float((uint)u << 16);
}
__device__ __forceinline__ ushort f2b(float f) {
  __hip_bfloat16 h = __float2bfloat16(f);  // RNE
  return *reinterpret_cast<ushort*>(&h);
}

// ---------------- CSR build (once per call, reused by all 4 layers) --------
__global__ void k_count(const int* __restrict__ ei, const int* __restrict__ eb,
                        int* __restrict__ cnt) {
  int e = blockIdx.x * 256 + threadIdx.x;
  if (e >= E_T) return;
  int dst = (e < E_I) ? ei[E_I + e] : eb[E_B + (e - E_I)];
  atomicAdd(&cnt[dst], 1);
}

__global__ void k_scan1(const int* __restrict__ cnt, int* __restrict__ tmp,
                        int* __restrict__ bsum) {
  int t = threadIdx.x;
  int lane = t & 63, wid = t >> 6;
  int base = blockIdx.x * 1024 + t * 4;
  int c[4];
#pragma unroll
  for (int i = 0; i < 4; ++i) c[i] = (base + i < N_I) ? cnt[base + i] : 0;
  int s = c[0] + c[1] + c[2] + c[3];
  int inc = s;
#pragma unroll
  for (int d = 1; d < 64; d <<= 1) {
    int u = __shfl_up(inc, d, 64);
    if (lane >= d) inc += u;
  }
  __shared__ int wtot[4];
  if (lane == 63) wtot[wid] = inc;
  __syncthreads();
  int woff = 0;
  for (int i = 0; i < wid; ++i) woff += wtot[i];
  int excl = woff + inc - s;
  int run = excl;
#pragma unroll
  for (int i = 0; i < 4; ++i) {
    if (base + i < N_I) tmp[base + i] = run;
    run += c[i];
  }
  if (t == 255) bsum[blockIdx.x] = woff + inc;
}

__global__ void k_scan2(int* bsum) {
  int t = threadIdx.x;  // 64 threads, 1 wave
  int v = (t < SCAN_NB) ? bsum[t] : 0;
  int inc = v;
#pragma unroll
  for (int d = 1; d < 64; d <<= 1) {
    int u = __shfl_up(inc, d, 64);
    if (t >= d) inc += u;
  }
  if (t < SCAN_NB) bsum[t] = inc - v;  // exclusive
}

// NOTE: tmp and cursor may alias (same-thread read-then-write) -> no restrict.
__global__ void k_scan3(const int* tmp, const int* bsum, int* offs, int* cursor) {
  int t = threadIdx.x;
  int base = blockIdx.x * 1024 + t * 4;
  int add = bsum[blockIdx.x];
#pragma unroll
  for (int i = 0; i < 4; ++i) {
    int idx = base + i;
    if (idx < N_I) {
      int v = tmp[idx] + add;
      offs[idx] = v;
      cursor[idx] = v;
    }
  }
  if (blockIdx.x == 0 && t == 0) offs[N_I] = E_T;
}

__global__ void k_fill(const int* __restrict__ ei, const int* __restrict__ eb,
                       int* __restrict__ cursor, int* __restrict__ csr) {
  int e = blockIdx.x * 256 + threadIdx.x;
  if (e >= E_T) return;
  int src, dst;
  if (e < E_I) {
    src = ei[e];
    dst = ei[E_I + e];
  } else {
    int j = e - E_I;
    src = eb[j];        // already >= N_I (global boundary id)
    dst = eb[E_B + j];
  }
  int pos = atomicAdd(&cursor[dst], 1);
  csr[pos] = src;
}

__global__ void k_zlist(const int* __restrict__ offs, int* __restrict__ zcnt,
                        int* __restrict__ zlist) {
  int v = blockIdx.x * 256 + threadIdx.x;
  if (v >= N_I) return;
  if (offs[v + 1] == offs[v]) {
    int p = atomicAdd(zcnt, 1);
    zlist[p] = v;
  }
}

// ---------------- boundary-value interpolation at t ------------------------
__global__ void k_bvt(const float* __restrict__ tptr, const float* __restrict__ ts,
                      const float* __restrict__ BV, float* __restrict__ out,
                      ushort* __restrict__ outh) {
  int idx = blockIdx.x * 256 + threadIdx.x;
  if (idx >= N_B * 64) return;
  float tv = tptr[0];
  int pos = 0;
#pragma unroll
  for (int i = 0; i < 8; ++i) pos += (ts[i] < tv) ? 1 : 0;  // searchsorted left
  int il = max(pos - 1, 0), ir = min(pos, 7);
  float tl = ts[il], tr = ts[ir];
  float vl = BV[il * (N_B * 64) + idx];
  float vr = BV[ir * (N_B * 64) + idx];
  bool eq = (tl == tr);
  float denom = eq ? 1.0f : (tr - tl);
  float v = eq ? vl : vl + (tv - tl) * (vr - vl) / denom;
  out[idx] = v;
  outh[idx] = f2b(v);
}

// ---------------- x_int fp32 -> bf16 hi ------------------------------------
__global__ void k_cvt(const float* __restrict__ in, ushort* __restrict__ oh, int n4) {
  int i = blockIdx.x * 256 + threadIdx.x;
  if (i >= n4) return;
  float4 v = reinterpret_cast<const float4*>(in)[i];
  ushort4 h;
  h.x = f2b(v.x); h.y = f2b(v.y); h.z = f2b(v.z); h.w = f2b(v.w);
  reinterpret_cast<ushort4*>(oh)[i] = h;
}

// ---------------- per-layer weight folding ---------------------------------
// M1 = Ws + Wu*Wm_dst, M2 = Wu*Wm_src, c1 = bs+bu+Wu*bm, c0 = bs+bu
// M1/M2 pre-split into bf16 hi/lo pairs, stored [o][k] row-major
// (MFMA B-frag = one contiguous 16B read). WsT fp32 [k][o] for bnd/fixup.
__global__ void k_fold(const float* __restrict__ Wm, const float* __restrict__ bm,
                       const float* __restrict__ Ws, const float* __restrict__ bs,
                       const float* __restrict__ Wu, const float* __restrict__ bu,
                       int d, int so,
                       ushort* __restrict__ M1h, ushort* __restrict__ M1l,
                       ushort* __restrict__ M2h, ushort* __restrict__ M2l,
                       float* __restrict__ WsT, float* __restrict__ c1,
                       float* __restrict__ c0) {
  int idx = blockIdx.x * 256 + threadIdx.x;
  if (idx < d * so) {
    int o = idx % so, k = idx / so;
    const float* wu = Wu + o * 128;
    float s1 = 0.f, s2 = 0.f;
    int tw = 2 * d;
    for (int j = 0; j < 128; ++j) {
      float u = wu[j];
      s1 = fmaf(u, Wm[j * tw + d + k], s1);
      s2 = fmaf(u, Wm[j * tw + k], s2);
    }
    float wsv = Ws[o * d + k];
    float m1 = wsv + s1;
    ushort h1 = f2b(m1);
    M1h[o * d + k] = h1;
    M1l[o * d + k] = f2b(m1 - b2f(h1));
    ushort h2 = f2b(s2);
    M2h[o * d + k] = h2;
    M2l[o * d + k] = f2b(s2 - b2f(h2));
    WsT[k * so + o] = wsv;
  }
  if (idx < so) {
    float s = 0.f;
    for (int j = 0; j < 128; ++j) s = fmaf(Wu[idx * 128 + j], bm[j], s);
    c1[idx] = bs[idx] + bu[idx] + s;
    c0[idx] = bs[idx] + bu[idx];
  }
}

// ---------------- scatter-mean of bf16-hi features (wave per node) ---------
// fp32 accumulate; result stored bf16-hi. 4-deep gather unroll for MLP.
template <int D>
__global__ void k_agg(const ushort* __restrict__ Xh, const ushort* __restrict__ BVh,
                      const int* __restrict__ csr, const int* __restrict__ offs,
                      ushort* __restrict__ Smh) {
  int v = blockIdx.x * 4 + (threadIdx.x >> 6);
  if (v >= N_I) return;
  int lane = threadIdx.x & 63;
  int o0 = offs[v], o1 = offs[v + 1];
  float a0 = 0.f, a1 = 0.f, b0 = 0.f, b1 = 0.f;
  float c0 = 0.f, c1 = 0.f, d0 = 0.f, d1 = 0.f;
  int p = o0;
  for (; p + 3 < o1; p += 4) {
    int s0 = csr[p], s1 = csr[p + 1], s2 = csr[p + 2], s3 = csr[p + 3];
    const ushort* f0 = (s0 < N_I) ? (Xh + (size_t)s0 * D) : (BVh + (size_t)(s0 - N_I) * D);
    const ushort* f1 = (s1 < N_I) ? (Xh + (size_t)s1 * D) : (BVh + (size_t)(s1 - N_I) * D);
    const ushort* f2 = (s2 < N_I) ? (Xh + (size_t)s2 * D) : (BVh + (size_t)(s2 - N_I) * D);
    const ushort* f3 = (s3 < N_I) ? (Xh + (size_t)s3 * D) : (BVh + (size_t)(s3 - N_I) * D);
    if (D == 128) {
      uint u0 = *reinterpret_cast<const uint*>(f0 + lane * 2);
      uint u1 = *reinterpret_cast<const uint*>(f1 + lane * 2);
      uint u2 = *reinterpret_cast<const uint*>(f2 + lane * 2);
      uint u3 = *reinterpret_cast<const uint*>(f3 + lane * 2);
      a0 += __uint_as_float(u0 << 16); a1 += __uint_as_float(u0 & 0xffff0000u);
      b0 += __uint_as_float(u1 << 16); b1 += __uint_as_float(u1 & 0xffff0000u);
      c0 += __uint_as_float(u2 << 16); c1 += __uint_as_float(u2 & 0xffff0000u);
      d0 += __uint_as_float(u3 << 16); d1 += __uint_as_float(u3 & 0xffff0000u);
    } else {
      a0 += b2f(f0[lane]); b0 += b2f(f1[lane]);
      c0 += b2f(f2[lane]); d0 += b2f(f3[lane]);
    }
  }
  for (; p < o1; ++p) {
    int s0 = csr[p];
    const ushort* f0 = (s0 < N_I) ? (Xh + (size_t)s0 * D) : (BVh + (size_t)(s0 - N_I) * D);
    if (D == 128) {
      uint u0 = *reinterpret_cast<const uint*>(f0 + lane * 2);
      a0 += __uint_as_float(u0 << 16);
      a1 += __uint_as_float(u0 & 0xffff0000u);
    } else {
      a0 += b2f(f0[lane]);
    }
  }
  float inv = 1.0f / (float)max(o1 - o0, 1);
  float m0 = ((a0 + b0) + (c0 + d0)) * inv;
  if (D == 128) {
    float m1 = ((a1 + b1) + (c1 + d1)) * inv;
    reinterpret_cast<uint*>(Smh + (size_t)v * D)[lane] =
        (uint)f2b(m0) | ((uint)f2b(m1) << 16);
  } else {
    Smh[(size_t)v * D + lane] = f2b(m0);
  }
}

// ---------------- node update GEMM: Y = act(X*M1^T + Sm*M2^T + c1) ---------
// One wave OWNS one 32-col tile (wave id); its B-fragments (hi+lo, both
// sources) live in VGPRs (loaded once), and the wave grid-strides over 32-row
// tiles. Split-bf16 weights, hi-only activations:
//   acc += Ah*Wh + Ah*Wl      (A-lo terms dropped; ~1e-3/layer error)
// Two accumulator chains (X-path with bias, Sm-path zero) summed at store.
// mfma_f32_32x32x16_bf16 layout:
//   A: row = lane&31, k = (lane>>5)*8 + e ;  B: col = lane&31, same k
//   C/D: col = lane&31, row = (r&3) + 8*(r>>2) + 4*(lane>>5)   [m74/m101]
template <int D, int SO, bool ACT>
__global__ __launch_bounds__(64 * (SO / 32), 2) void k_mm(
    const ushort* __restrict__ Xh, const ushort* __restrict__ Sh,
    const ushort* __restrict__ M1h, const ushort* __restrict__ M1l,
    const ushort* __restrict__ M2h, const ushort* __restrict__ M2l,
    const float* __restrict__ c1, ushort* __restrict__ Yh,
    float* __restrict__ Yf) {
  constexpr int KS = D / 16;
  int wid = threadIdx.x >> 6;  // this wave's col-tile
  int lane = threadIdx.x & 63;
  int l31 = lane & 31, hi5 = lane >> 5;
  int col = wid * 32 + l31;
  size_t wbase = (size_t)col * D + hi5 * 8;
  // Resident weights: 4*KS fragments.
  short8 w1h[KS], w1l[KS], w2h[KS], w2l[KS];
#pragma unroll
  for (int ks = 0; ks < KS; ++ks) {
    w1h[ks] = *reinterpret_cast<const short8*>(M1h + wbase + ks * 16);
    w1l[ks] = *reinterpret_cast<const short8*>(M1l + wbase + ks * 16);
    w2h[ks] = *reinterpret_cast<const short8*>(M2h + wbase + ks * 16);
    w2l[ks] = *reinterpret_cast<const short8*>(M2l + wbase + ks * 16);
  }
  float bias = c1[col];
  for (int rt = blockIdx.x; rt < NTILES; rt += MM_GRID) {
    int row = rt * 32 + l31;
    int rrow = min(row, N_I - 1);  // clamp loads; stores are bounds-checked
    size_t abase = (size_t)rrow * D + hi5 * 8;
    f32x16 accA, accB;
#pragma unroll
    for (int r = 0; r < 16; ++r) {
      accA[r] = bias;
      accB[r] = 0.0f;
    }
#pragma unroll
    for (int ks = 0; ks < KS; ++ks) {
      short8 xh = *reinterpret_cast<const short8*>(Xh + abase + ks * 16);
      short8 sh = *reinterpret_cast<const short8*>(Sh + abase + ks * 16);
      accA = __builtin_amdgcn_mfma_f32_32x32x16_bf16(xh, w1h[ks], accA, 0, 0, 0);
      accB = __builtin_amdgcn_mfma_f32_32x32x16_bf16(sh, w2h[ks], accB, 0, 0, 0);
      accA = __builtin_amdgcn_mfma_f32_32x32x16_bf16(xh, w1l[ks], accA, 0, 0, 0);
      accB = __builtin_amdgcn_mfma_f32_32x32x16_bf16(sh, w2l[ks], accB, 0, 0, 0);
    }
#pragma unroll
    for (int r = 0; r < 16; ++r) {
      int rit = (r & 3) + 8 * (r >> 2) + 4 * hi5;
      int grow = rt * 32 + rit;
      if (grow < N_I) {
        float v = accA[r] + accB[r];
        if (ACT) {
          v = softplusf(v);
          Yh[(size_t)grow * SO + col] = f2b(v);
        } else {
          Yf[(size_t)grow * SO + col] = v;
        }
      }
    }
  }
}

// ---------------- deg==0 fixup: y = act(Ws*x + c0) -------------------------
template <int D, int SO, bool ACT>
__global__ void k_fix(const int* __restrict__ zcnt, const int* __restrict__ zlist,
                      const ushort* __restrict__ Xh, const float* __restrict__ WsT,
                      const float* __restrict__ c0, ushort* __restrict__ Yh,
                      float* __restrict__ Yf) {
  int nz = zcnt[0];
  int o = threadIdx.x;
  if (o >= SO) return;
  for (int i = 0; i < nz; ++i) {
    int v = zlist[i];
    float s = c0[o];
    for (int k = 0; k < D; ++k)
      s = fmaf(WsT[k * SO + o], b2f(Xh[(size_t)v * D + k]), s);
    if (ACT) {
      s = softplusf(s);
      Yh[(size_t)v * SO + o] = f2b(s);
    } else {
      Yf[(size_t)v * SO + o] = s;
    }
  }
}

// ---------------- boundary update: bv' = softplus(Ws*bv + bs) --------------
// fp32 in/out (for next k_bnd) + bf16-hi copy (for next k_agg gather).
template <int D, int SO>
__global__ void k_bnd(const float* __restrict__ BVin, const float* __restrict__ WsT,
                      const float* __restrict__ bs, float* __restrict__ out,
                      ushort* __restrict__ outh) {
  constexpr int TPN = SO / 4;
  constexpr int NPB = 256 / TPN;
  __shared__ float lx[NPB * D];
  int t = threadIdx.x;
  int base = blockIdx.x * NPB;
  for (int i = t; i < NPB * D; i += 256) lx[i] = BVin[(size_t)base * D + i];
  __syncthreads();
  int g = t / TPN;
  int o = (t % TPN) * 4;
  int v = base + g;
  float4 acc = make_float4(bs[o], bs[o + 1], bs[o + 2], bs[o + 3]);
  const float* xr = lx + g * D;
  const float4* W4 = reinterpret_cast<const float4*>(WsT);
#pragma unroll 8
  for (int k = 0; k < D; ++k) {
    float4 w = W4[k * (SO / 4) + (o >> 2)];
    float xv = xr[k];
    acc.x = fmaf(xv, w.x, acc.x);
    acc.y = fmaf(xv, w.y, acc.y);
    acc.z = fmaf(xv, w.z, acc.z);
    acc.w = fmaf(xv, w.w, acc.w);
  }
  float4 ov;
  ov.x = softplusf(acc.x);
  ov.y = softplusf(acc.y);
  ov.z = softplusf(acc.z);
  ov.w = softplusf(acc.w);
  reinterpret_cast<float4*>(out + (size_t)v * SO)[o >> 2] = ov;
  ushort4 oh;
  oh.x = f2b(ov.x); oh.y = f2b(ov.y); oh.z = f2b(ov.z); oh.w = f2b(ov.w);
  reinterpret_cast<ushort4*>(outh + (size_t)v * SO)[o >> 2] = oh;
}

extern "C" void kernel_launch(void* const* d_in, const int* in_sizes, int n_in,
                              void* d_out, int out_size, void* d_ws, size_t ws_size,
                              hipStream_t stream) {
  const float* t_in = (const float*)d_in[0];
  const float* x_int = (const float*)d_in[1];
  const float* bvals = (const float*)d_in[2];
  const int* ei = (const int*)d_in[3];
  const int* eb = (const int*)d_in[4];
  const float* ts = (const float*)d_in[5];
  const float* W[4][6];
  for (int l = 0; l < 4; ++l)
    for (int j = 0; j < 6; ++j) W[l][j] = (const float*)d_in[6 + l * 6 + j];
  // j: 0=Wm 1=bm 2=Ws 3=bs 4=Wu 5=bu

  char* ws = (char*)d_ws;
  size_t off = 0;
  auto alloc = [&](size_t bytes) {
    void* p = ws + off;
    off = (off + bytes + 255) & ~(size_t)255;
    return p;
  };
  int* cnt = (int*)alloc(N_I * 4);
  int* offs = (int*)alloc((N_I + 1) * 4);
  int* cursor = (int*)alloc(N_I * 4);
  int* csr = (int*)alloc((size_t)E_T * 4);
  int* bsum = (int*)alloc(64 * 4);
  int* zcnt = (int*)alloc(4);
  int* zlist = (int*)alloc(N_I * 4);
  // Activation ping-pong, bf16 hi.
  ushort* Ah = (ushort*)alloc((size_t)N_I * 128 * 2);
  ushort* Bh = (ushort*)alloc((size_t)N_I * 128 * 2);
  ushort* Smh = (ushort*)alloc((size_t)N_I * 128 * 2);
  float* bv1 = (float*)alloc((size_t)N_B * 64 * 4);
  float* bv2 = (float*)alloc((size_t)N_B * 128 * 4);
  float* bv3 = (float*)alloc((size_t)N_B * 128 * 4);
  float* bv4 = (float*)alloc((size_t)N_B * 128 * 4);
  ushort* bvh1 = (ushort*)alloc((size_t)N_B * 64 * 2);
  ushort* bvh2 = (ushort*)alloc((size_t)N_B * 128 * 2);
  ushort* bvh3 = (ushort*)alloc((size_t)N_B * 128 * 2);
  ushort* bvh4 = (ushort*)alloc((size_t)N_B * 128 * 2);
  ushort *M1h[4], *M1l[4], *M2h[4], *M2l[4];
  float *WsT[4], *c1[4], *c0[4];
  for (int l = 0; l < 4; ++l) {
    M1h[l] = (ushort*)alloc(16384 * 2);
    M1l[l] = (ushort*)alloc(16384 * 2);
    M2h[l] = (ushort*)alloc(16384 * 2);
    M2l[l] = (ushort*)alloc(16384 * 2);
    WsT[l] = (float*)alloc(16384 * 4);
    c1[l] = (float*)alloc(128 * 4);
    c0[l] = (float*)alloc(128 * 4);
  }
  (void)ws_size; (void)in_sizes; (void)n_in; (void)out_size;

  hipMemsetAsync(cnt, 0, N_I * 4, stream);
  hipMemsetAsync(zcnt, 0, 4, stream);
  int egrid = (E_T + 255) / 256;
  k_count<<<egrid, 256, 0, stream>>>(ei, eb, cnt);
  k_scan1<<<SCAN_NB, 256, 0, stream>>>(cnt, cursor /*tmp*/, bsum);
  k_scan2<<<1, 64, 0, stream>>>(bsum);
  k_scan3<<<SCAN_NB, 256, 0, stream>>>(cursor, bsum, offs, cursor);
  k_fill<<<egrid, 256, 0, stream>>>(ei, eb, cursor, csr);
  k_zlist<<<(N_I + 255) / 256, 256, 0, stream>>>(offs, zcnt, zlist);
  k_bvt<<<(N_B * 64 + 255) / 256, 256, 0, stream>>>(t_in, ts, bvals, bv1, bvh1);
  k_cvt<<<(N_I * 64 / 4 + 255) / 256, 256, 0, stream>>>(x_int, Ah, N_I * 64 / 4);

  int ds[4] = {64, 128, 128, 128};
  int sos[4] = {128, 128, 128, 64};
  for (int l = 0; l < 4; ++l) {
    int tot = ds[l] * sos[l];
    k_fold<<<(tot + 255) / 256, 256, 0, stream>>>(
        W[l][0], W[l][1], W[l][2], W[l][3], W[l][4], W[l][5], ds[l], sos[l],
        M1h[l], M1l[l], M2h[l], M2l[l], WsT[l], c1[l], c0[l]);
  }

  constexpr int BND_GRID = N_B / 8;  // NPB==8 for all layers -> 250

  // Layer 1: D=64 -> 128   (reads Ah as [N_I][64], writes Bh [N_I][128])
  k_agg<64><<<N_I / 4, 256, 0, stream>>>(Ah, bvh1, csr, offs, Smh);
  k_mm<64, 128, true><<<MM_GRID, 256, 0, stream>>>(Ah, Smh, M1h[0], M1l[0], M2h[0],
                                                   M2l[0], c1[0], Bh, nullptr);
  k_fix<64, 128, true><<<1, 128, 0, stream>>>(zcnt, zlist, Ah, WsT[0], c0[0], Bh,
                                              nullptr);
  k_bnd<64, 128><<<BND_GRID, 256, 0, stream>>>(bv1, WsT[0], W[0][3], bv2, bvh2);

  // Layer 2: 128 -> 128    (reads Bh, overwrites Ah)
  k_agg<128><<<N_I / 4, 256, 0, stream>>>(Bh, bvh2, csr, offs, Smh);
  k_mm<128, 128, true><<<MM_GRID, 256, 0, stream>>>(Bh, Smh, M1h[1], M1l[1], M2h[1],
                                                    M2l[1], c1[1], Ah, nullptr);
  k_fix<128, 128, true><<<1, 128, 0, stream>>>(zcnt, zlist, Bh, WsT[1], c0[1], Ah,
                                               nullptr);
  k_bnd<128, 128><<<BND_GRID, 256, 0, stream>>>(bv2, WsT[1], W[1][3], bv3, bvh3);

  // Layer 3: 128 -> 128    (reads Ah, writes Bh)
  k_agg<128><<<N_I / 4, 256, 0, stream>>>(Ah, bvh3, csr, offs, Smh);
  k_mm<128, 128, true><<<MM_GRID, 256, 0, stream>>>(Ah, Smh, M1h[2], M1l[2], M2h[2],
                                                    M2l[2], c1[2], Bh, nullptr);
  k_fix<128, 128, true><<<1, 128, 0, stream>>>(zcnt, zlist, Ah, WsT[2], c0[2], Bh,
                                               nullptr);
  k_bnd<128, 128><<<BND_GRID, 256, 0, stream>>>(bv3, WsT[2], W[2][3], bv4, bvh4);

  // Layer 4: 128 -> 64, no activation, fp32 straight to d_out
  k_agg<128><<<N_I / 4, 256, 0, stream>>>(Bh, bvh4, csr, offs, Smh);
  k_mm<128, 64, false><<<MM_GRID, 128, 0, stream>>>(Bh, Smh, M1h[3], M1l[3], M2h[3],
                                                    M2l[3], c1[3], nullptr,
                                                    (float*)d_out);
  k_fix<128, 64, false><<<1, 128, 0, stream>>>(zcnt, zlist, Bh, WsT[3], c0[3], nullptr,
                                               (float*)d_out);
}

// Round 7
// 446.056 us; speedup vs baseline: 2.3967x; 1.1010x over previous
//
#include <hip/hip_runtime.h>
#include <hip/hip_bf16.h>
#include <math.h>

// Problem constants (fixed by the reference).
constexpr int N_I = 50000;   // interior nodes
constexpr int N_B = 2000;    // boundary nodes
constexpr int E_I = 800000;  // interior edges
constexpr int E_B = 16000;   // boundary edges
constexpr int E_T = E_I + E_B;
constexpr int SCAN_NB = (N_I + 1023) / 1024;  // 49
constexpr int NTILES = (N_I + 31) / 32;       // 1563 row-tiles
constexpr int MM_GRID = 512;                  // 2 blocks/CU, grid-stride tiles

using short8 = __attribute__((ext_vector_type(8))) short;
using f32x16 = __attribute__((ext_vector_type(16))) float;

__device__ __forceinline__ float softplusf(float x) {
  return fmaxf(x, 0.0f) + log1pf(expf(-fabsf(x)));
}
__device__ __forceinline__ float b2f(ushort u) {
  return __uint_as_float((uint)u << 16);
}
__device__ __forceinline__ ushort f2b(float f) {
  __hip_bfloat16 h = __float2bfloat16(f);  // RNE
  return *reinterpret_cast<ushort*>(&h);
}
// async global->LDS, 16B per lane; LDS dest = wave-uniform base + lane*16.
__device__ __forceinline__ void gl_lds16(const void* g, void* l) {
  __builtin_amdgcn_global_load_lds(
      (const __attribute__((address_space(1))) void*)g,
      (__attribute__((address_space(3))) void*)l, 16, 0, 0);
}

// ---------------- CSR build (once per call, reused by all 4 layers) --------
__global__ void k_count(const int* __restrict__ ei, const int* __restrict__ eb,
                        int* __restrict__ cnt) {
  int e = blockIdx.x * 256 + threadIdx.x;
  if (e >= E_T) return;
  int dst = (e < E_I) ? ei[E_I + e] : eb[E_B + (e - E_I)];
  atomicAdd(&cnt[dst], 1);
}

__global__ void k_scan1(const int* __restrict__ cnt, int* __restrict__ tmp,
                        int* __restrict__ bsum) {
  int t = threadIdx.x;
  int lane = t & 63, wid = t >> 6;
  int base = blockIdx.x * 1024 + t * 4;
  int c[4];
#pragma unroll
  for (int i = 0; i < 4; ++i) c[i] = (base + i < N_I) ? cnt[base + i] : 0;
  int s = c[0] + c[1] + c[2] + c[3];
  int inc = s;
#pragma unroll
  for (int d = 1; d < 64; d <<= 1) {
    int u = __shfl_up(inc, d, 64);
    if (lane >= d) inc += u;
  }
  __shared__ int wtot[4];
  if (lane == 63) wtot[wid] = inc;
  __syncthreads();
  int woff = 0;
  for (int i = 0; i < wid; ++i) woff += wtot[i];
  int excl = woff + inc - s;
  int run = excl;
#pragma unroll
  for (int i = 0; i < 4; ++i) {
    if (base + i < N_I) tmp[base + i] = run;
    run += c[i];
  }
  if (t == 255) bsum[blockIdx.x] = woff + inc;
}

__global__ void k_scan2(int* bsum) {
  int t = threadIdx.x;  // 64 threads, 1 wave
  int v = (t < SCAN_NB) ? bsum[t] : 0;
  int inc = v;
#pragma unroll
  for (int d = 1; d < 64; d <<= 1) {
    int u = __shfl_up(inc, d, 64);
    if (t >= d) inc += u;
  }
  if (t < SCAN_NB) bsum[t] = inc - v;  // exclusive
}

// NOTE: tmp and cursor may alias (same-thread read-then-write) -> no restrict.
__global__ void k_scan3(const int* tmp, const int* bsum, int* offs, int* cursor) {
  int t = threadIdx.x;
  int base = blockIdx.x * 1024 + t * 4;
  int add = bsum[blockIdx.x];
#pragma unroll
  for (int i = 0; i < 4; ++i) {
    int idx = base + i;
    if (idx < N_I) {
      int v = tmp[idx] + add;
      offs[idx] = v;
      cursor[idx] = v;
    }
  }
  if (blockIdx.x == 0 && t == 0) offs[N_I] = E_T;
}

__global__ void k_fill(const int* __restrict__ ei, const int* __restrict__ eb,
                       int* __restrict__ cursor, int* __restrict__ csr) {
  int e = blockIdx.x * 256 + threadIdx.x;
  if (e >= E_T) return;
  int src, dst;
  if (e < E_I) {
    src = ei[e];
    dst = ei[E_I + e];
  } else {
    int j = e - E_I;
    src = eb[j];        // already >= N_I (global boundary id)
    dst = eb[E_B + j];
  }
  int pos = atomicAdd(&cursor[dst], 1);
  csr[pos] = src;
}

__global__ void k_zlist(const int* __restrict__ offs, int* __restrict__ zcnt,
                        int* __restrict__ zlist) {
  int v = blockIdx.x * 256 + threadIdx.x;
  if (v >= N_I) return;
  if (offs[v + 1] == offs[v]) {
    int p = atomicAdd(zcnt, 1);
    zlist[p] = v;
  }
}

// ---------------- boundary-value interpolation at t ------------------------
__global__ void k_bvt(const float* __restrict__ tptr, const float* __restrict__ ts,
                      const float* __restrict__ BV, float* __restrict__ out,
                      ushort* __restrict__ outh) {
  int idx = blockIdx.x * 256 + threadIdx.x;
  if (idx >= N_B * 64) return;
  float tv = tptr[0];
  int pos = 0;
#pragma unroll
  for (int i = 0; i < 8; ++i) pos += (ts[i] < tv) ? 1 : 0;  // searchsorted left
  int il = max(pos - 1, 0), ir = min(pos, 7);
  float tl = ts[il], tr = ts[ir];
  float vl = BV[il * (N_B * 64) + idx];
  float vr = BV[ir * (N_B * 64) + idx];
  bool eq = (tl == tr);
  float denom = eq ? 1.0f : (tr - tl);
  float v = eq ? vl : vl + (tv - tl) * (vr - vl) / denom;
  out[idx] = v;
  outh[idx] = f2b(v);
}

// ---------------- x_int fp32 -> bf16 hi ------------------------------------
__global__ void k_cvt(const float* __restrict__ in, ushort* __restrict__ oh, int n4) {
  int i = blockIdx.x * 256 + threadIdx.x;
  if (i >= n4) return;
  float4 v = reinterpret_cast<const float4*>(in)[i];
  ushort4 h;
  h.x = f2b(v.x); h.y = f2b(v.y); h.z = f2b(v.z); h.w = f2b(v.w);
  reinterpret_cast<ushort4*>(oh)[i] = h;
}

// ---------------- per-layer weight folding ---------------------------------
// M1 = Ws + Wu*Wm_dst, M2 = Wu*Wm_src, c1 = bs+bu+Wu*bm, c0 = bs+bu
// M1/M2 split bf16 hi/lo, stored in MFMA-FRAGMENT order so k_mm weight loads
// are lane-contiguous (coalesced 1KB):
//   (o,k) -> (((ct*KS + ks)*2 + hi)*32 + l)*8 + e
//   ct=o>>5, l=o&31, ks=k>>4, hi=(k>>3)&1, e=k&7, KS=d/16.
// WsT fp32 [k][o] for bnd/fixup.
__global__ void k_fold(const float* __restrict__ Wm, const float* __restrict__ bm,
                       const float* __restrict__ Ws, const float* __restrict__ bs,
                       const float* __restrict__ Wu, const float* __restrict__ bu,
                       int d, int so,
                       ushort* __restrict__ M1h, ushort* __restrict__ M1l,
                       ushort* __restrict__ M2h, ushort* __restrict__ M2l,
                       float* __restrict__ WsT, float* __restrict__ c1,
                       float* __restrict__ c0) {
  int idx = blockIdx.x * 256 + threadIdx.x;
  if (idx < d * so) {
    int o = idx % so, k = idx / so;
    const float* wu = Wu + o * 128;
    float s1 = 0.f, s2 = 0.f;
    int tw = 2 * d;
    for (int j = 0; j < 128; ++j) {
      float u = wu[j];
      s1 = fmaf(u, Wm[j * tw + d + k], s1);
      s2 = fmaf(u, Wm[j * tw + k], s2);
    }
    float wsv = Ws[o * d + k];
    int KSr = d >> 4;
    int fo = ((((o >> 5) * KSr + (k >> 4)) * 2 + ((k >> 3) & 1)) * 32 + (o & 31)) * 8 +
             (k & 7);
    float m1 = wsv + s1;
    ushort h1 = f2b(m1);
    M1h[fo] = h1;
    M1l[fo] = f2b(m1 - b2f(h1));
    ushort h2 = f2b(s2);
    M2h[fo] = h2;
    M2l[fo] = f2b(s2 - b2f(h2));
    WsT[k * so + o] = wsv;
  }
  if (idx < so) {
    float s = 0.f;
    for (int j = 0; j < 128; ++j) s = fmaf(Wu[idx * 128 + j], bm[j], s);
    c1[idx] = bs[idx] + bu[idx] + s;
    c0[idx] = bs[idx] + bu[idx];
  }
}

// ---------------- scatter-mean of bf16-hi features (wave per node) ---------
// fp32 accumulate; result stored bf16-hi. 8-deep gather unroll for MLP.
template <int D>
__global__ void k_agg(const ushort* __restrict__ Xh, const ushort* __restrict__ BVh,
                      const int* __restrict__ csr, const int* __restrict__ offs,
                      ushort* __restrict__ Smh) {
  int v = blockIdx.x * 4 + (threadIdx.x >> 6);
  if (v >= N_I) return;
  int lane = threadIdx.x & 63;
  int o0 = offs[v], o1 = offs[v + 1];
  float a0 = 0.f, a1 = 0.f;
  int p = o0;
  int nfull = o0 + ((o1 - o0) & ~7);
  for (; p < nfull; p += 8) {
    uint u[8];
    ushort w[8];
#pragma unroll
    for (int j = 0; j < 8; ++j) {
      int s = csr[p + j];  // wave-uniform
      const ushort* f =
          (s < N_I) ? (Xh + (size_t)s * D) : (BVh + (size_t)(s - N_I) * D);
      if (D == 128)
        u[j] = *reinterpret_cast<const uint*>(f + lane * 2);
      else
        w[j] = f[lane];
    }
#pragma unroll
    for (int j = 0; j < 8; ++j) {
      if (D == 128) {
        a0 += __uint_as_float(u[j] << 16);
        a1 += __uint_as_float(u[j] & 0xffff0000u);
      } else {
        a0 += b2f(w[j]);
      }
    }
  }
  for (; p < o1; ++p) {
    int s = csr[p];
    const ushort* f = (s < N_I) ? (Xh + (size_t)s * D) : (BVh + (size_t)(s - N_I) * D);
    if (D == 128) {
      uint u0 = *reinterpret_cast<const uint*>(f + lane * 2);
      a0 += __uint_as_float(u0 << 16);
      a1 += __uint_as_float(u0 & 0xffff0000u);
    } else {
      a0 += b2f(f[lane]);
    }
  }
  float inv = 1.0f / (float)max(o1 - o0, 1);
  float m0 = a0 * inv;
  if (D == 128) {
    float m1 = a1 * inv;
    reinterpret_cast<uint*>(Smh + (size_t)v * D)[lane] =
        (uint)f2b(m0) | ((uint)f2b(m1) << 16);
  } else {
    Smh[(size_t)v * D + lane] = f2b(m0);
  }
}

// ---------------- node update GEMM: Y = act(X*M1^T + Sm*M2^T + c1) ---------
// Block = SO/32 waves; wave owns col-tile wid (weights VGPR-resident or
// coalesced-reloaded: fragment order). A-tiles (X and Sm, 32 rows) are LDS-
// staged per row-tile via global_load_lds w=16 with XOR-swizzled global
// source (chunk ^= row&7), double-buffered, one barrier/iter. ds_read_b128
// at the same swizzle -> 4-way residual bank aliasing only.
// Split-bf16 weights, hi-only activations: acc += Ah*Wh + Ah*Wl.
// mfma_f32_32x32x16_bf16: A row=lane&31, k=(lane>>5)*8+e; B col=lane&31;
// C/D col=lane&31, row=(r&3)+8*(r>>2)+4*(lane>>5)   [m74/m101]
template <int D, int SO, bool ACT>
__global__ __launch_bounds__(64 * (SO / 32), 2) void k_mm(
    const ushort* __restrict__ Xh, const ushort* __restrict__ Sh,
    const ushort* __restrict__ M1h, const ushort* __restrict__ M1l,
    const ushort* __restrict__ M2h, const ushort* __restrict__ M2l,
    const float* __restrict__ c1, ushort* __restrict__ Yh,
    float* __restrict__ Yf) {
  constexpr int KS = D / 16;        // MFMA K-steps
  constexpr int CR = D / 8;         // 16B chunks per row
  constexpr int TC = 32 * CR;       // chunks per 32-row tile
  constexpr int W = SO / 32;        // waves per block
  constexpr int CPW = TC / (64 * W);  // gl_lds calls per wave per array
  __shared__ ushort ldsX[2][32 * D];
  __shared__ ushort ldsS[2][32 * D];
  int tid = threadIdx.x;
  int wid = tid >> 6, lane = tid & 63;
  int l31 = lane & 31, hi5 = lane >> 5;
  int col = wid * 32 + l31;
  // Fragment-order weight loads: per-lane 16B contiguous, wave-coalesced.
  short8 w1h[KS], w1l[KS], w2h[KS], w2l[KS];
#pragma unroll
  for (int ks = 0; ks < KS; ++ks) {
    size_t fo = (size_t)(((wid * KS + ks) * 2 + hi5) * 32 + l31) * 8;
    w1h[ks] = *reinterpret_cast<const short8*>(M1h + fo);
    w1l[ks] = *reinterpret_cast<const short8*>(M1l + fo);
    w2h[ks] = *reinterpret_cast<const short8*>(M2h + fo);
    w2l[ks] = *reinterpret_cast<const short8*>(M2l + fo);
  }
  float bias = c1[col];

  auto stage = [&](int buf, int rt) {
#pragma unroll
    for (int i = 0; i < CPW; ++i) {
      int q0 = (i * W + wid) * 64;   // wave-uniform chunk base
      int q = q0 + lane;             // this lane's chunk
      int r = q / CR, cp = q % CR;
      int cs = cp ^ (r & 7);         // pre-swizzled source chunk
      int rg = min(rt * 32 + r, N_I - 1);
      gl_lds16(Xh + (size_t)rg * D + cs * 8, &ldsX[buf][q0 * 8]);
      gl_lds16(Sh + (size_t)rg * D + cs * 8, &ldsS[buf][q0 * 8]);
    }
  };

  int rt0 = blockIdx.x;
  stage(0, rt0);
  int buf = 0;
  for (int rt = rt0; rt < NTILES; rt += MM_GRID) {
    __syncthreads();  // stage(buf) visible to all waves (drains vmcnt)
    int rtn = rt + MM_GRID;
    if (rtn < NTILES) stage(buf ^ 1, rtn);  // prefetch overlaps compute
    f32x16 accA, accB;
#pragma unroll
    for (int r = 0; r < 16; ++r) {
      accA[r] = bias;
      accB[r] = 0.0f;
    }
#pragma unroll
    for (int ks = 0; ks < KS; ++ks) {
      int c = (ks * 2 + hi5) ^ (l31 & 7);  // swizzled chunk
      const short8 xh = *reinterpret_cast<const short8*>(&ldsX[buf][(l31 * CR + c) * 8]);
      const short8 sh = *reinterpret_cast<const short8*>(&ldsS[buf][(l31 * CR + c) * 8]);
      accA = __builtin_amdgcn_mfma_f32_32x32x16_bf16(xh, w1h[ks], accA, 0, 0, 0);
      accB = __builtin_amdgcn_mfma_f32_32x32x16_bf16(sh, w2h[ks], accB, 0, 0, 0);
      accA = __builtin_amdgcn_mfma_f32_32x32x16_bf16(xh, w1l[ks], accA, 0, 0, 0);
      accB = __builtin_amdgcn_mfma_f32_32x32x16_bf16(sh, w2l[ks], accB, 0, 0, 0);
    }
#pragma unroll
    for (int r = 0; r < 16; ++r) {
      int rit = (r & 3) + 8 * (r >> 2) + 4 * hi5;
      int grow = rt * 32 + rit;
      if (grow < N_I) {
        float v = accA[r] + accB[r];
        if (ACT) {
          v = softplusf(v);
          Yh[(size_t)grow * SO + col] = f2b(v);
        } else {
          Yf[(size_t)grow * SO + col] = v;
        }
      }
    }
    buf ^= 1;
  }
}

// ---------------- deg==0 fixup: y = act(Ws*x + c0) -------------------------
template <int D, int SO, bool ACT>
__global__ void k_fix(const int* __restrict__ zcnt, const int* __restrict__ zlist,
                      const ushort* __restrict__ Xh, const float* __restrict__ WsT,
                      const float* __restrict__ c0, ushort* __restrict__ Yh,
                      float* __restrict__ Yf) {
  int nz = zcnt[0];
  int o = threadIdx.x;
  if (o >= SO) return;
  for (int i = 0; i < nz; ++i) {
    int v = zlist[i];
    float s = c0[o];
    for (int k = 0; k < D; ++k)
      s = fmaf(WsT[k * SO + o], b2f(Xh[(size_t)v * D + k]), s);
    if (ACT) {
      s = softplusf(s);
      Yh[(size_t)v * SO + o] = f2b(s);
    } else {
      Yf[(size_t)v * SO + o] = s;
    }
  }
}

// ---------------- boundary update: bv' = softplus(Ws*bv + bs) --------------
// fp32 in/out (for next k_bnd) + bf16-hi copy (for next k_agg gather).
template <int D, int SO>
__global__ void k_bnd(const float* __restrict__ BVin, const float* __restrict__ WsT,
                      const float* __restrict__ bs, float* __restrict__ out,
                      ushort* __restrict__ outh) {
  constexpr int TPN = SO / 4;
  constexpr int NPB = 256 / TPN;
  __shared__ float lx[NPB * D];
  int t = threadIdx.x;
  int base = blockIdx.x * NPB;
  for (int i = t; i < NPB * D; i += 256) lx[i] = BVin[(size_t)base * D + i];
  __syncthreads();
  int g = t / TPN;
  int o = (t % TPN) * 4;
  int v = base + g;
  float4 acc = make_float4(bs[o], bs[o + 1], bs[o + 2], bs[o + 3]);
  const float* xr = lx + g * D;
  const float4* W4 = reinterpret_cast<const float4*>(WsT);
#pragma unroll 8
  for (int k = 0; k < D; ++k) {
    float4 w = W4[k * (SO / 4) + (o >> 2)];
    float xv = xr[k];
    acc.x = fmaf(xv, w.x, acc.x);
    acc.y = fmaf(xv, w.y, acc.y);
    acc.z = fmaf(xv, w.z, acc.z);
    acc.w = fmaf(xv, w.w, acc.w);
  }
  float4 ov;
  ov.x = softplusf(acc.x);
  ov.y = softplusf(acc.y);
  ov.z = softplusf(acc.z);
  ov.w = softplusf(acc.w);
  reinterpret_cast<float4*>(out + (size_t)v * SO)[o >> 2] = ov;
  ushort4 oh;
  oh.x = f2b(ov.x); oh.y = f2b(ov.y); oh.z = f2b(ov.z); oh.w = f2b(ov.w);
  reinterpret_cast<ushort4*>(outh + (size_t)v * SO)[o >> 2] = oh;
}

extern "C" void kernel_launch(void* const* d_in, const int* in_sizes, int n_in,
                              void* d_out, int out_size, void* d_ws, size_t ws_size,
                              hipStream_t stream) {
  const float* t_in = (const float*)d_in[0];
  const float* x_int = (const float*)d_in[1];
  const float* bvals = (const float*)d_in[2];
  const int* ei = (const int*)d_in[3];
  const int* eb = (const int*)d_in[4];
  const float* ts = (const float*)d_in[5];
  const float* W[4][6];
  for (int l = 0; l < 4; ++l)
    for (int j = 0; j < 6; ++j) W[l][j] = (const float*)d_in[6 + l * 6 + j];
  // j: 0=Wm 1=bm 2=Ws 3=bs 4=Wu 5=bu

  char* ws = (char*)d_ws;
  size_t off = 0;
  auto alloc = [&](size_t bytes) {
    void* p = ws + off;
    off = (off + bytes + 255) & ~(size_t)255;
    return p;
  };
  int* cnt = (int*)alloc(N_I * 4);
  int* offs = (int*)alloc((N_I + 1) * 4);
  int* cursor = (int*)alloc(N_I * 4);
  int* csr = (int*)alloc((size_t)E_T * 4);
  int* bsum = (int*)alloc(64 * 4);
  int* zcnt = (int*)alloc(4);
  int* zlist = (int*)alloc(N_I * 4);
  // Activation ping-pong, bf16 hi.
  ushort* Ah = (ushort*)alloc((size_t)N_I * 128 * 2);
  ushort* Bh = (ushort*)alloc((size_t)N_I * 128 * 2);
  ushort* Smh = (ushort*)alloc((size_t)N_I * 128 * 2);
  float* bv1 = (float*)alloc((size_t)N_B * 64 * 4);
  float* bv2 = (float*)alloc((size_t)N_B * 128 * 4);
  float* bv3 = (float*)alloc((size_t)N_B * 128 * 4);
  float* bv4 = (float*)alloc((size_t)N_B * 128 * 4);
  ushort* bvh1 = (ushort*)alloc((size_t)N_B * 64 * 2);
  ushort* bvh2 = (ushort*)alloc((size_t)N_B * 128 * 2);
  ushort* bvh3 = (ushort*)alloc((size_t)N_B * 128 * 2);
  ushort* bvh4 = (ushort*)alloc((size_t)N_B * 128 * 2);
  ushort *M1h[4], *M1l[4], *M2h[4], *M2l[4];
  float *WsT[4], *c1[4], *c0[4];
  for (int l = 0; l < 4; ++l) {
    M1h[l] = (ushort*)alloc(16384 * 2);
    M1l[l] = (ushort*)alloc(16384 * 2);
    M2h[l] = (ushort*)alloc(16384 * 2);
    M2l[l] = (ushort*)alloc(16384 * 2);
    WsT[l] = (float*)alloc(16384 * 4);
    c1[l] = (float*)alloc(128 * 4);
    c0[l] = (float*)alloc(128 * 4);
  }
  (void)ws_size; (void)in_sizes; (void)n_in; (void)out_size;

  hipMemsetAsync(cnt, 0, N_I * 4, stream);
  hipMemsetAsync(zcnt, 0, 4, stream);
  int egrid = (E_T + 255) / 256;
  k_count<<<egrid, 256, 0, stream>>>(ei, eb, cnt);
  k_scan1<<<SCAN_NB, 256, 0, stream>>>(cnt, cursor /*tmp*/, bsum);
  k_scan2<<<1, 64, 0, stream>>>(bsum);
  k_scan3<<<SCAN_NB, 256, 0, stream>>>(cursor, bsum, offs, cursor);
  k_fill<<<egrid, 256, 0, stream>>>(ei, eb, cursor, csr);
  k_zlist<<<(N_I + 255) / 256, 256, 0, stream>>>(offs, zcnt, zlist);
  k_bvt<<<(N_B * 64 + 255) / 256, 256, 0, stream>>>(t_in, ts, bvals, bv1, bvh1);
  k_cvt<<<(N_I * 64 / 4 + 255) / 256, 256, 0, stream>>>(x_int, Ah, N_I * 64 / 4);

  int ds[4] = {64, 128, 128, 128};
  int sos[4] = {128, 128, 128, 64};
  for (int l = 0; l < 4; ++l) {
    int tot = ds[l] * sos[l];
    k_fold<<<(tot + 255) / 256, 256, 0, stream>>>(
        W[l][0], W[l][1], W[l][2], W[l][3], W[l][4], W[l][5], ds[l], sos[l],
        M1h[l], M1l[l], M2h[l], M2l[l], WsT[l], c1[l], c0[l]);
  }

  constexpr int BND_GRID = N_B / 8;  // NPB==8 for all layers -> 250

  // Layer 1: D=64 -> 128   (reads Ah as [N_I][64], writes Bh [N_I][128])
  k_agg<64><<<N_I / 4, 256, 0, stream>>>(Ah, bvh1, csr, offs, Smh);
  k_mm<64, 128, true><<<MM_GRID, 256, 0, stream>>>(Ah, Smh, M1h[0], M1l[0], M2h[0],
                                                   M2l[0], c1[0], Bh, nullptr);
  k_fix<64, 128, true><<<1, 128, 0, stream>>>(zcnt, zlist, Ah, WsT[0], c0[0], Bh,
                                              nullptr);
  k_bnd<64, 128><<<BND_GRID, 256, 0, stream>>>(bv1, WsT[0], W[0][3], bv2, bvh2);

  // Layer 2: 128 -> 128    (reads Bh, overwrites Ah)
  k_agg<128><<<N_I / 4, 256, 0, stream>>>(Bh, bvh2, csr, offs, Smh);
  k_mm<128, 128, true><<<MM_GRID, 256, 0, stream>>>(Bh, Smh, M1h[1], M1l[1], M2h[1],
                                                    M2l[1], c1[1], Ah, nullptr);
  k_fix<128, 128, true><<<1, 128, 0, stream>>>(zcnt, zlist, Bh, WsT[1], c0[1], Ah,
                                               nullptr);
  k_bnd<128, 128><<<BND_GRID, 256, 0, stream>>>(bv2, WsT[1], W[1][3], bv3, bvh3);

  // Layer 3: 128 -> 128    (reads Ah, writes Bh)
  k_agg<128><<<N_I / 4, 256, 0, stream>>>(Ah, bvh3, csr, offs, Smh);
  k_mm<128, 128, true><<<MM_GRID, 256, 0, stream>>>(Ah, Smh, M1h[2], M1l[2], M2h[2],
                                                    M2l[2], c1[2], Bh, nullptr);
  k_fix<128, 128, true><<<1, 128, 0, stream>>>(zcnt, zlist, Ah, WsT[2], c0[2], Bh,
                                               nullptr);
  k_bnd<128, 128><<<BND_GRID, 256, 0, stream>>>(bv3, WsT[2], W[2][3], bv4, bvh4);

  // Layer 4: 128 -> 64, no activation, fp32 straight to d_out
  k_agg<128><<<N_I / 4, 256, 0, stream>>>(Bh, bvh4, csr, offs, Smh);
  k_mm<128, 64, false><<<MM_GRID, 128, 0, stream>>>(Bh, Smh, M1h[3], M1l[3], M2h[3],
                                                    M2l[3], c1[3], nullptr,
                                                    (float*)d_out);
  k_fix<128, 64, false><<<1, 128, 0, stream>>>(zcnt, zlist, Bh, WsT[3], c0[3], nullptr,
                                               (float*)d_out);
}